// Round 12
// baseline (286.944 us; speedup 1.0000x reference)
//
#include <hip/hip_runtime.h>
#include <stdint.h>

// Problem constants
#define AA 144          // ATOM*ATOM
#define LAM 0.1f

// ---- workspace layout (float offsets) ----
#define OFS_SC    0            // 64 scalars: [16]=scX, [17]=scA
#define OFS_AF1   64           // 128*144 row-normalized zero-mean atoms
#define OFS_AF1T  18496        // 144*128 transposed
#define OFS_G     36928        // 128*128 gram (f32)
#define OFS_S0    53312        // ATB (bf16 atoms, [128][160] u16)
#define OFS_S1    69696        // ANTBPI (bf16 atomsT, pos-permuted k, [144][128] u16)
#define OFS_X     86080        // XPBI: bf16 X, pos-permuted k, [128][136] u16
#define OFS_PM    139328       // 32768 patch means
#define OFS_GOAL  172096       // 45056 goal (f32)
#define OFS_CF    4411456      // cfT [128][32768]
#define OFS_PRED  8605760      // predT [144][32768]
#define OFS_ATB   OFS_S0
#define OFS_ANTB  OFS_S1

typedef __attribute__((ext_vector_type(4))) short short4_t;
typedef __attribute__((ext_vector_type(8))) short short8_t;
typedef __attribute__((ext_vector_type(4))) float f32x4;

// Guard only on the DEVICE pass: __has_builtin for amdgcn builtins is false on
// the host pass (R11 failure: #error fired "compiling for host" while the
// gfx950 pass accepted it).
#if defined(__HIP_DEVICE_COMPILE__) && !__has_builtin(__builtin_amdgcn_mfma_f32_16x16x16bf16_1k)
#error "mfma 16x16x16 bf16 1k builtin unavailable on this device target"
#endif

__device__ __forceinline__ unsigned short f2bf(float f) {      // RNE
    union { float f; uint32_t u; } x; x.f = f;
    uint32_t u = x.u;
    return (unsigned short)((u + 0x7FFFu + ((u >> 16) & 1u)) >> 16);
}
__device__ __forceinline__ float bf2f(unsigned short u) {
    union { float f; uint32_t i; } x; x.i = ((uint32_t)u) << 16; return x.f;
}
// pack two f32 -> packed bf16 pair (a->low, b->high), round-half-up
__device__ __forceinline__ uint32_t pack_bf(float a, float b) {
    union { float f; uint32_t u; } xa, xb; xa.f = a; xb.f = b;
    return __builtin_amdgcn_perm(xb.u + 0x8000u, xa.u + 0x8000u, 0x07060302u);
}
// XI/ANTBPI interleave: position pos within a 128-wide k-row maps to
// k = ((pos&31)>>2)*16 + (pos>>5)*4 + (pos&3); one b128 read at
// quad*32+sp*8 then yields A-frags (K=16) of tiles s=2sp and 2sp+1.
__device__ __forceinline__ int pos2k(int pos) {
    return (((pos & 31) >> 2) << 4) + ((pos >> 5) << 2) + (pos & 3);
}

// ---- setup: per-atom zero-mean unit-norm rows -> Af1, Af1T ----
__global__ __launch_bounds__(256) void k_norm(const float* atoms, float* ws) {
    int t = threadIdx.x;
    if (t < 128) {
        const float* ap = atoms + t * AA;
        float s = 0.f;
        for (int k = 0; k < AA; ++k) s += ap[k];
        float mean = s * (1.0f / 144.0f);
        float ss = 0.f;
        for (int k = 0; k < AA; ++k) { float a = ap[k] - mean; ss = fmaf(a, a, ss); }
        float rn = 1.0f / sqrtf(ss);
        for (int k = 0; k < AA; ++k) {
            float a = (ap[k] - mean) * rn;
            ws[OFS_AF1  + t * AA + k] = a;
            ws[OFS_AF1T + k * 128 + t] = a;
        }
    }
}

// ---- G = Af1 @ Af1^T ----
__global__ __launch_bounds__(256) void k_gram(float* ws) {
    __shared__ float Ai[8 * AA];
    int t = threadIdx.x;
    int i0 = blockIdx.x * 8;
    for (int e = t; e < 8 * AA; e += 256) Ai[e] = ws[OFS_AF1 + i0 * AA + e];
    __syncthreads();
    int ti = t >> 5, tj = t & 31;
    float a0 = 0, a1 = 0, a2 = 0, a3 = 0;
    for (int k = 0; k < AA; ++k) {
        float a = Ai[ti * AA + k];
        float4 bv = *(const float4*)&ws[OFS_AF1T + k * 128 + tj * 4];
        a0 = fmaf(a, bv.x, a0); a1 = fmaf(a, bv.y, a1);
        a2 = fmaf(a, bv.z, a2); a3 = fmaf(a, bv.w, a3);
    }
    *(float4*)&ws[OFS_G + (i0 + ti) * 128 + tj * 4] = make_float4(a0, a1, a2, a3);
}

// ---- fused spectral norm: 8x bf16 MFMA squarings (one block) + f32 Rayleigh ----
#define PSTR 136
__global__ __launch_bounds__(256) void k_power(const float* G, const float* mu_p, float* sc) {
    __shared__ unsigned short Pb[2][128 * PSTR];
    __shared__ float tr_arr[10];
    __shared__ float v[128];
    __shared__ float red[256];
    int t = threadIdx.x;
    int lane = t & 63, w = t >> 6;
    int col = lane & 15, quad = lane >> 4;
    if (t < 10) tr_arr[t] = (t == 0) ? 128.0f : 0.f;
    for (int i = 0; i < 64; ++i) {
        int e = t + i * 256;                  // 16384
        int m = e >> 7, ks = e & 127;
        int g = ks >> 5, rem = ks & 31, u = rem >> 1, vv = rem & 1;
        int k = g * 32 + vv * 16 + u;
        Pb[0][m * PSTR + ks] = f2bf(G[m * 128 + k]);
    }
    __syncthreads();
    int cur = 0;
    #pragma unroll 1
    for (int j = 0; j < 8; ++j) {
        float trn = tr_arr[j];
        float inv2 = 1.0f / (trn * trn);
        const unsigned short* S = Pb[cur];
        uint32_t* D32 = (uint32_t*)Pb[cur ^ 1];     // row stride 68 u32
        short8_t bf[2][4];
        #pragma unroll
        for (int nt = 0; nt < 2; ++nt)
            #pragma unroll
            for (int s = 0; s < 4; ++s)
                bf[nt][s] = *(const short8_t*)&S[(32 * w + nt * 16 + col) * PSTR + s * 32 + quad * 8];
        int n0 = 32 * w + col, n1 = n0 + 16;
        #pragma unroll
        for (int mt = 0; mt < 8; ++mt) {
            short8_t af[4];
            #pragma unroll
            for (int s = 0; s < 4; ++s)
                af[s] = *(const short8_t*)&S[(mt * 16 + col) * PSTR + s * 32 + quad * 8];
            f32x4 a0 = (f32x4){0.f, 0.f, 0.f, 0.f};
            f32x4 a1 = (f32x4){0.f, 0.f, 0.f, 0.f};
            #pragma unroll
            for (int s = 0; s < 4; ++s) {
                a0 = __builtin_amdgcn_mfma_f32_16x16x32_bf16(af[s], bf[0][s], a0, 0, 0, 0);
                a1 = __builtin_amdgcn_mfma_f32_16x16x32_bf16(af[s], bf[1][s], a1, 0, 0, 0);
            }
            #pragma unroll
            for (int r = 0; r < 4; ++r) {
                float x0 = a0[r] * inv2, x1 = a1[r] * inv2;
                int row = mt * 16 + quad * 4 + r;
                D32[row * 68 + 16 * w + col] = pack_bf(x0, x1);
                if (row == n0) atomicAdd(&tr_arr[j + 1], x0);
                if (row == n1) atomicAdd(&tr_arr[j + 1], x1);
            }
        }
        __syncthreads();
        cur ^= 1;
    }
    if (t < 128) {
        const unsigned short* S = Pb[cur];
        float s = 0.f;
        for (int k = 0; k < 128; ++k) s += bf2f(S[t * PSTR + k]);
        v[t] = s;
    }
    __syncthreads();
    if (t < 128) {
        float wv = 0.f;
        for (int k = 0; k < 128; ++k) wv = fmaf(G[t * 128 + k], v[k], wv);
        red[t] = v[t] * wv;
        red[128 + t] = v[t] * v[t];
    }
    __syncthreads();
    for (int off = 64; off > 0; off >>= 1) {
        if (t < off) { red[t] += red[t + off]; red[128 + t] += red[128 + t + off]; }
        __syncthreads();
    }
    if (t == 0) {
        float lam = red[0] / red[128];               // sigma^2 = lammax(G)
        float mu = fmaxf(mu_p[0], 0.0f);
        sc[16] = 1.0f / (lam * mu);                  // X scale
        sc[17] = 1.0f / (sqrtf(lam) * sqrtf(mu));    // atom scale
    }
}

// ---- finalize: XPBI ; ATB ; ANTBPI ; goal ; pm ----
__global__ __launch_bounds__(256) void k_finalize(float* ws, const float* y) {
    int idx = blockIdx.x * 256 + threadIdx.x;       // grid 396 -> 101376
    float scX = ws[OFS_SC + 16], scA = ws[OFS_SC + 17];
    if (idx < 17408) {                              // XPBI [128][136] u16
        int n = idx / 136, posp = idx - n * 136;
        float v = (posp < 128) ? ws[OFS_G + n * 128 + pos2k(posp)] * scX : 0.f;
        ((unsigned short*)(ws + OFS_X))[idx] = f2bf(v);
    } else if (idx < 37888) {
        int e = idx - 17408;                        // ATB [n=128][k=160] zero-pad
        int n = e / 160, k = e - n * 160;
        float v = (k < 144) ? ws[OFS_AF1 + n * 144 + k] * scA : 0.f;
        ((unsigned short*)(ws + OFS_ATB))[e] = f2bf(v);
    } else if (idx < 56320) {
        int e = idx - 37888;                        // ANTBPI [j=144][pos=128]
        int jp = e >> 7, pos = e & 127;
        ((unsigned short*)(ws + OFS_ANTB))[e] =
            f2bf(ws[OFS_AF1 + pos2k(pos) * 144 + jp] * scA);
    } else {
        int e = idx - 56320;                        // < 45056
        if (e < 45000) ws[OFS_GOAL + e] = y[e];
        if (e < 32768) {
            int b = e >> 12, pi = (e >> 6) & 63, pj = e & 63;
            const float* yb = y + b * 5625;
            float s = 0.f;
            for (int di = 0; di < 12; ++di) {
                const float* row = yb + (pi + di) * 75 + pj;
                #pragma unroll
                for (int dj = 0; dj < 12; ++dj) s += row[dj];
            }
            ws[OFS_PM + e] = s * (1.0f / 144.0f);
        }
    }
}

// ---- barrier-free megakernel: q + FISTA(15)+1 + pred, state in registers.
//      Block = 64 patches (b,pi); wave w owns patches p0+16w..+15 (col dim).
//      State orientation transposed: tiles S_s[n'=s*16+quad*4+r][p=col];
//      C/D tile == K=16 B-operand, so the loop never touches LDS. ----
__global__ __launch_bounds__(256) void k_fista(
        const unsigned short* XPBI, const float* goal,
        const unsigned short* ATB, const unsigned short* ANTBPI,
        const float* pm, float* cfT, float* predT,
        const float* mu_p, int first, int write_cf) {
    __shared__ union __align__(16) {
        struct { float gls[12 * 76]; unsigned short Atile[64 * 168]; } qp;
        unsigned short XI[128 * 136];
        float4 XI4[2176];
    } sm;
    int t = threadIdx.x;
    int lane = t & 63, w = t >> 6;
    int col = lane & 15, quad = lane >> 4;
    int blk = blockIdx.x;
    int b = blk >> 6, pi = blk & 63;
    int pw = blk * 64 + w * 16 + col;              // this lane's patch
    float mu = fmaxf(mu_p[0], 0.0f);

    // ---- phase A: goal row slice ----
    for (int e = t; e < 912; e += 256) {
        int r = e / 76, cc = e - r * 76;
        sm.qp.gls[e] = (cc < 75) ? goal[b * 5625 + (pi + r) * 75 + cc] : 0.f;
    }
    __syncthreads();
    // im2col A-tile 64x168 u16, pair-packed
    {
        uint32_t* A32 = (uint32_t*)sm.qp.Atile;    // row stride 84 u32
        #pragma unroll
        for (int i = 0; i < 20; ++i) {
            int pe = t + i * 256;                  // < 5120 = 64m*80
            int m = pe / 80, q32 = pe - m * 80;
            int kk = q32 * 2;
            float v0 = 0.f, v1 = 0.f;
            if (kk < 144) {
                int di = kk / 12, dj = kk - di * 12;
                v0 = sm.qp.gls[di * 76 + m + dj];
                int k1 = kk + 1, di1 = k1 / 12, dj1 = k1 - di1 * 12;
                v1 = sm.qp.gls[di1 * 76 + m + dj1];
            }
            A32[m * 84 + q32] = pack_bf(v0, v1);
        }
    }
    __syncthreads();
    // B-frags (this wave's 16 patches) then free Atile
    short8_t bq[5];
    #pragma unroll
    for (int s = 0; s < 5; ++s)
        bq[s] = *(const short8_t*)&sm.qp.Atile[(w * 16 + col) * 168 + s * 32 + quad * 8];
    __syncthreads();                               // all waves took bq; Atile dead

    // XI copy (overwrites union) — overlaps with q matmul below
    {
        const float4* src = (const float4*)XPBI;
        #pragma unroll
        for (int i = 0; i < 9; ++i) {
            int e = t + i * 256;
            if (e < 2176) sm.XI4[e] = src[e];
        }
    }

    // q^T matmul: qv[s][r] = q[pw][n = s*16+quad*4+r]   (A=ATB, B=im2col)
    float qv[8][4];
    #pragma unroll
    for (int mt = 0; mt < 8; ++mt) {
        f32x4 a = (f32x4){0.f, 0.f, 0.f, 0.f};
        #pragma unroll
        for (int s = 0; s < 5; ++s) {
            short8_t af = *(const short8_t*)&ATB[(mt * 16 + col) * 160 + s * 32 + quad * 8];
            a = __builtin_amdgcn_mfma_f32_16x16x32_bf16(af, bq[s], a, 0, 0, 0);
        }
        #pragma unroll
        for (int r = 0; r < 4; ++r) qv[mt][r] = a[r];
    }
    __syncthreads();                               // XI visible to all waves

    // ---- state init ----
    float cv[8][4], zo[8][4];
    __align__(16) uint32_t zb[8][2];
    if (first) {
        #pragma unroll
        for (int s = 0; s < 8; ++s) {
            #pragma unroll
            for (int r = 0; r < 4; ++r) { cv[s][r] = 0.f; zo[s][r] = 0.f; }
            zb[s][0] = 0u; zb[s][1] = 0u;
        }
    } else {
        #pragma unroll
        for (int s = 0; s < 8; ++s) {
            #pragma unroll
            for (int r = 0; r < 4; ++r) {
                float c = cfT[(s * 16 + quad * 4 + r) * 32768 + pw];
                cv[s][r] = c; zo[s][r] = c;
            }
            zb[s][0] = pack_bf(zo[s][0], zo[s][1]);
            zb[s][1] = pack_bf(zo[s][2], zo[s][3]);
        }
    }

    float acc[8][4];
    auto matmul = [&]() {                          // T = X @ Z^T, all-register B
        #pragma unroll
        for (int mt = 0; mt < 8; ++mt) {
            f32x4 a = (f32x4){0.f, 0.f, 0.f, 0.f};
            #pragma unroll
            for (int sp = 0; sp < 4; ++sp) {
                short8_t x2 = *(const short8_t*)&sm.XI[(mt * 16 + col) * 136 + quad * 32 + sp * 8];
                short4_t xlo = __builtin_shufflevector(x2, x2, 0, 1, 2, 3);
                short4_t xhi = __builtin_shufflevector(x2, x2, 4, 5, 6, 7);
                a = __builtin_amdgcn_mfma_f32_16x16x16bf16_1k(
                        xlo, *(const short4_t*)&zb[2 * sp][0], a, 0, 0, 0);
                a = __builtin_amdgcn_mfma_f32_16x16x16bf16_1k(
                        xhi, *(const short4_t*)&zb[2 * sp + 1][0], a, 0, 0, 0);
            }
            #pragma unroll
            for (int r = 0; r < 4; ++r) acc[mt][r] = a[r];
        }
    };

    float tm = 1.0f;
    #pragma unroll 1
    for (int it = 0; it < 14; ++it) {              // FISTA iters 1..14
        matmul();
        float tnn = 0.5f * (1.0f + sqrtf(1.0f + 4.0f * tm * tm));
        float fm = (tm - 1.0f) / tnn;
        tm = tnn;
        #pragma unroll
        for (int s = 0; s < 8; ++s) {
            float zn[4];
            #pragma unroll
            for (int r = 0; r < 4; ++r) {
                float df = qv[s][r] - acc[s][r];
                float u = fmaf(mu, df, zo[s][r]);
                float cl = fminf(fmaxf(u, -LAM), LAM);
                float cn = u - cl;
                float d = cn - cv[s][r];
                float z = fmaf(fm, d, cn);
                cv[s][r] = cn;
                zo[s][r] = z;
                zn[r] = z;
            }
            zb[s][0] = pack_bf(zn[0], zn[1]);
            zb[s][1] = pack_bf(zn[2], zn[3]);
        }
    }
    {   // FISTA iter 15: c15 (z15 never consumed)
        matmul();
        #pragma unroll
        for (int s = 0; s < 8; ++s) {
            #pragma unroll
            for (int r = 0; r < 4; ++r) {
                float df = qv[s][r] - acc[s][r];
                float u = fmaf(mu, df, zo[s][r]);
                float cl = fminf(fmaxf(u, -LAM), LAM);
                cv[s][r] = u - cl;
            }
            zb[s][0] = pack_bf(cv[s][0], cv[s][1]);
            zb[s][1] = pack_bf(cv[s][2], cv[s][3]);
        }
    }
    {   // final differentiable step: cf = prox(c15 + mu*(q - X@c15))
        matmul();
        #pragma unroll
        for (int s = 0; s < 8; ++s) {
            #pragma unroll
            for (int r = 0; r < 4; ++r) {
                float df = qv[s][r] - acc[s][r];
                float u = fmaf(mu, df, cv[s][r]);
                float cl = fminf(fmaxf(u, -LAM), LAM);
                float cf = u - cl;
                cv[s][r] = cf;
                if (write_cf) cfT[(s * 16 + quad * 4 + r) * 32768 + pw] = cf;
            }
            zb[s][0] = pack_bf(cv[s][0], cv[s][1]);
            zb[s][1] = pack_bf(cv[s][2], cv[s][3]);
        }
    }

    // ---- pred tail: predT[j][pw] = (cf @ atoms_n)^T + pm  (A=ANTBPI, B=cf-state) ----
    {
        float pmv = pm[pw];
        #pragma unroll
        for (int jt = 0; jt < 9; ++jt) {
            f32x4 a = (f32x4){0.f, 0.f, 0.f, 0.f};
            #pragma unroll
            for (int sp = 0; sp < 4; ++sp) {
                short8_t x2 = *(const short8_t*)&ANTBPI[(jt * 16 + col) * 128 + quad * 32 + sp * 8];
                short4_t xlo = __builtin_shufflevector(x2, x2, 0, 1, 2, 3);
                short4_t xhi = __builtin_shufflevector(x2, x2, 4, 5, 6, 7);
                a = __builtin_amdgcn_mfma_f32_16x16x16bf16_1k(
                        xlo, *(const short4_t*)&zb[2 * sp][0], a, 0, 0, 0);
                a = __builtin_amdgcn_mfma_f32_16x16x16bf16_1k(
                        xhi, *(const short4_t*)&zb[2 * sp + 1][0], a, 0, 0, 0);
            }
            #pragma unroll
            for (int r = 0; r < 4; ++r)
                predT[(jt * 16 + quad * 4 + r) * 32768 + pw] = a[r] + pmv;
        }
    }
}

// ---- fold via LDS staging from predT (coalesced 64-wide runs) ----
__global__ __launch_bounds__(256) void k_fold(const float* y, const float* beta_p,
                                              const float* predT, float* goal,
                                              float* out, int write_out) {
    __shared__ float P[12 * 832];              // 39,936 B
    int i = blockIdx.x, b = blockIdx.y;
    int t = threadIdx.x;
    for (int di = 0; di < 12; ++di) {
        int pi = i - di;
        if ((unsigned)pi >= 64u) continue;     // uniform per block
        int base = (b << 12) + (pi << 6);
        #pragma unroll
        for (int it = 0; it < 3; ++it) {
            int e = t + it * 256;              // < 768 = 12 dj * 64 pj
            int dj = e >> 6, pj = e & 63;
            P[di * 832 + pj * 13 + dj] = predT[(di * 12 + dj) * 32768 + base + pj];
        }
    }
    __syncthreads();
    if (t >= 75) return;
    int j = t;
    float S = 0.f;
    for (int di = 0; di < 12; ++di) {
        if ((unsigned)(i - di) >= 64u) continue;
        const float* Pd = &P[di * 832];
        #pragma unroll
        for (int dj = 0; dj < 12; ++dj) {
            int pj = j - dj;
            if ((unsigned)pj >= 64u) continue;
            S += Pd[pj * 13 + dj];
        }
    }
    int ci = min(i, 11) - max(i - 63, 0) + 1;
    int cj = min(j, 11) - max(j - 63, 0) + 1;
    float beta = fmaxf(beta_p[0], 0.0f);
    int idx = i * 75 + j;
    float yv = y[b * 5625 + idx];
    float g = (yv + beta * S) / (1.0f + beta * (float)(ci * cj));
    if (write_out) out[b * 5625 + idx] = g;
    else           goal[b * 5625 + idx] = g;
}

extern "C" void kernel_launch(void* const* d_in, const int* in_sizes, int n_in,
                              void* d_out, int out_size, void* d_ws, size_t ws_size,
                              hipStream_t stream) {
    const float* y     = (const float*)d_in[0];
    const float* atoms = (const float*)d_in[1];
    const float* beta  = (const float*)d_in[2];
    const float* mu    = (const float*)d_in[3];
    float* out = (float*)d_out;
    float* ws = (float*)d_ws;

    k_norm<<<1, 256, 0, stream>>>(atoms, ws);
    k_gram<<<16, 256, 0, stream>>>(ws);
    k_power<<<1, 256, 0, stream>>>(ws + OFS_G, mu, ws + OFS_SC);
    k_finalize<<<396, 256, 0, stream>>>(ws, y);     // XPBI + ATB + ANTBPI + goal + pm

    for (int u = 0; u < 2; ++u) {
        k_fista<<<512, 256, 0, stream>>>((const unsigned short*)(ws + OFS_X),
                                         ws + OFS_GOAL,
                                         (const unsigned short*)(ws + OFS_ATB),
                                         (const unsigned short*)(ws + OFS_ANTB),
                                         ws + OFS_PM, ws + OFS_CF, ws + OFS_PRED,
                                         mu, u == 0 ? 1 : 0, u == 0 ? 1 : 0);
        k_fold<<<dim3(75, 8), 256, 0, stream>>>(y, beta, ws + OFS_PRED,
                                                ws + OFS_GOAL, out, u == 1 ? 1 : 0);
    }
}

// Round 13
// 251.091 us; speedup vs baseline: 1.1428x; 1.1428x over previous
//
#include <hip/hip_runtime.h>
#include <stdint.h>

// Problem constants
#define AA 144          // ATOM*ATOM
#define LAM 0.1f

// ---- workspace layout (float offsets) ----
#define OFS_SC    0            // 64 scalars: [16]=scX, [17]=scA
#define OFS_AF1   64           // 128*144 row-normalized zero-mean atoms
#define OFS_G     36928        // 128*128 gram (f32)
#define OFS_S0    53312        // ATB (bf16 atoms, [128][160] u16)
#define OFS_S1    69696        // ANTBP (bf16 atomsT, n-permuted, [144][128] u16)
#define OFS_X     86080        // XPB: bf16 X, k-permuted, [128][128] u16
#define OFS_PM    139328       // 32768 patch means
#define OFS_GOAL  172096       // 45056 goal (f32)
#define OFS_CF    4411456      // 32768*128
#define OFS_PRED  8605760      // 32768*144
#define OFS_ATB   OFS_S0
#define OFS_ANTB  OFS_S1

// Contraction-dim permutation: real n = 32g + 16v + u  <->  stored ks = 32g + 2u + v.
// A and B sides both use stored order -> dot products unchanged.

typedef __attribute__((ext_vector_type(8))) short short8_t;
typedef __attribute__((ext_vector_type(4))) float f32x4;

__device__ __forceinline__ unsigned short f2bf(float f) {      // RNE
    union { float f; uint32_t u; } x; x.f = f;
    uint32_t u = x.u;
    return (unsigned short)((u + 0x7FFFu + ((u >> 16) & 1u)) >> 16);
}
__device__ __forceinline__ float bf2f(unsigned short u) {
    union { float f; uint32_t i; } x; x.i = ((uint32_t)u) << 16; return x.f;
}
// pack two f32 -> packed bf16 pair (a->low, b->high), round-half-up
__device__ __forceinline__ uint32_t pack_bf(float a, float b) {
    union { float f; uint32_t u; } xa, xb; xa.f = a; xb.f = b;
    return __builtin_amdgcn_perm(xb.u + 0x8000u, xa.u + 0x8000u, 0x07060302u);
}

// ---- fused setup: atom norm -> bf16 gram (MFMA) -> 8x power squarings -> Rayleigh.
//      One block. Gram seeds both f32 G (global) and the bf16 power buffer. ----
#define PSTR 136
__global__ __launch_bounds__(256) void k_setup(const float* atoms, const float* mu_p,
                                               float* ws) {
    __shared__ unsigned short ABf[128 * 168];       // 43008 B
    __shared__ unsigned short Pb[2][128 * PSTR];    // 69632 B
    __shared__ float tr_arr[10];
    __shared__ float v[128];
    __shared__ float red[256];
    int t = threadIdx.x;
    int lane = t & 63, w = t >> 6;
    int col = lane & 15, quad = lane >> 4;
    if (t < 10) tr_arr[t] = (t == 0) ? 128.0f : 0.f;
    // ---- norm: per-atom zero-mean unit-norm rows -> AF1 (f32) + ABf (bf16, LDS) ----
    if (t < 128) {
        const float* ap = atoms + t * AA;
        float s = 0.f;
        for (int k = 0; k < AA; ++k) s += ap[k];
        float mean = s * (1.0f / 144.0f);
        float ss = 0.f;
        for (int k = 0; k < AA; ++k) { float a = ap[k] - mean; ss = fmaf(a, a, ss); }
        float rn = 1.0f / sqrtf(ss);
        for (int k = 0; k < AA; ++k) {
            float a = (ap[k] - mean) * rn;
            ws[OFS_AF1 + t * AA + k] = a;
            ABf[t * 168 + k] = f2bf(a);
        }
        for (int k = AA; k < 160; ++k) ABf[t * 168 + k] = 0;
    }
    __syncthreads();
    // ---- gram: G = A@A^T via bf16 MFMA (A and B frags are the same rows) ----
    {
        uint32_t* D32 = (uint32_t*)Pb[0];           // row stride 68 u32 (permuted cols)
        float* G = ws + OFS_G;
        #pragma unroll 1
        for (int g = 0; g < 4; ++g) {
            short8_t b0[5], b1[5];
            #pragma unroll
            for (int s = 0; s < 5; ++s) {
                b0[s] = *(const short8_t*)&ABf[((2 * g) * 16 + col) * 168 + s * 32 + quad * 8];
                b1[s] = *(const short8_t*)&ABf[((2 * g + 1) * 16 + col) * 168 + s * 32 + quad * 8];
            }
            #pragma unroll
            for (int mi = 0; mi < 2; ++mi) {
                int mt = 2 * w + mi;
                short8_t af[5];
                #pragma unroll
                for (int s = 0; s < 5; ++s)
                    af[s] = *(const short8_t*)&ABf[(mt * 16 + col) * 168 + s * 32 + quad * 8];
                f32x4 a0 = (f32x4){0.f, 0.f, 0.f, 0.f};
                f32x4 a1 = (f32x4){0.f, 0.f, 0.f, 0.f};
                #pragma unroll
                for (int s = 0; s < 5; ++s) {
                    a0 = __builtin_amdgcn_mfma_f32_16x16x32_bf16(af[s], b0[s], a0, 0, 0, 0);
                    a1 = __builtin_amdgcn_mfma_f32_16x16x32_bf16(af[s], b1[s], a1, 0, 0, 0);
                }
                #pragma unroll
                for (int r = 0; r < 4; ++r) {
                    int m = mt * 16 + quad * 4 + r;
                    G[m * 128 + g * 32 + col] = a0[r];           // k = g*32 + 0*16 + col
                    G[m * 128 + g * 32 + 16 + col] = a1[r];      // k = g*32 + 1*16 + col
                    D32[m * 68 + g * 16 + col] = pack_bf(a0[r], a1[r]);  // ks = g*32+2*col+v
                }
            }
        }
    }
    __syncthreads();
    // ---- power: 8 trace-normalized squarings (ping-pong) ----
    int cur = 0;
    #pragma unroll 1
    for (int j = 0; j < 8; ++j) {
        float trn = tr_arr[j];
        float inv2 = 1.0f / (trn * trn);
        const unsigned short* S = Pb[cur];
        uint32_t* D32 = (uint32_t*)Pb[cur ^ 1];     // row stride 68 u32
        short8_t bf[2][4];
        #pragma unroll
        for (int nt = 0; nt < 2; ++nt)
            #pragma unroll
            for (int s = 0; s < 4; ++s)
                bf[nt][s] = *(const short8_t*)&S[(32 * w + nt * 16 + col) * PSTR + s * 32 + quad * 8];
        int n0 = 32 * w + col, n1 = n0 + 16;
        #pragma unroll
        for (int mt = 0; mt < 8; ++mt) {
            short8_t af[4];
            #pragma unroll
            for (int s = 0; s < 4; ++s)
                af[s] = *(const short8_t*)&S[(mt * 16 + col) * PSTR + s * 32 + quad * 8];
            f32x4 a0 = (f32x4){0.f, 0.f, 0.f, 0.f};
            f32x4 a1 = (f32x4){0.f, 0.f, 0.f, 0.f};
            #pragma unroll
            for (int s = 0; s < 4; ++s) {
                a0 = __builtin_amdgcn_mfma_f32_16x16x32_bf16(af[s], bf[0][s], a0, 0, 0, 0);
                a1 = __builtin_amdgcn_mfma_f32_16x16x32_bf16(af[s], bf[1][s], a1, 0, 0, 0);
            }
            #pragma unroll
            for (int r = 0; r < 4; ++r) {
                float x0 = a0[r] * inv2, x1 = a1[r] * inv2;
                int row = mt * 16 + quad * 4 + r;
                D32[row * 68 + 16 * w + col] = pack_bf(x0, x1);
                if (row == n0) atomicAdd(&tr_arr[j + 1], x0);
                if (row == n1) atomicAdd(&tr_arr[j + 1], x1);
            }
        }
        __syncthreads();
        cur ^= 1;
    }
    // ---- Rayleigh on f32 G: v = P*ones; lam = v'Gv / v'v ----
    if (t < 128) {
        const unsigned short* S = Pb[cur];
        float s = 0.f;
        for (int k = 0; k < 128; ++k) s += bf2f(S[t * PSTR + k]);
        v[t] = s;
    }
    __syncthreads();
    if (t < 128) {
        const float* G = ws + OFS_G;
        float wv = 0.f;
        for (int k = 0; k < 128; ++k) wv = fmaf(G[t * 128 + k], v[k], wv);
        red[t] = v[t] * wv;
        red[128 + t] = v[t] * v[t];
    }
    __syncthreads();
    for (int off = 64; off > 0; off >>= 1) {
        if (t < off) { red[t] += red[t + off]; red[128 + t] += red[128 + t + off]; }
        __syncthreads();
    }
    if (t == 0) {
        float lam = red[0] / red[128];               // sigma^2 = lammax(G)
        float mu = fmaxf(mu_p[0], 0.0f);
        ws[OFS_SC + 16] = 1.0f / (lam * mu);                  // X scale
        ws[OFS_SC + 17] = 1.0f / (sqrtf(lam) * sqrtf(mu));    // atom scale
    }
}

// ---- finalize: XPB (bf16, k-permuted) ; ATB ; ANTBP (n-permuted) ; goal ; pm ----
__global__ __launch_bounds__(256) void k_finalize(float* ws, const float* y) {
    int idx = blockIdx.x * 256 + threadIdx.x;       // grid 392 -> 100352
    float scX = ws[OFS_SC + 16], scA = ws[OFS_SC + 17];
    if (idx < 16384) {
        int n = idx >> 7, ks = idx & 127;
        int g = ks >> 5, rem = ks & 31, u = rem >> 1, v = rem & 1;
        int k = g * 32 + v * 16 + u;                // pi^-1(ks)
        ((unsigned short*)(ws + OFS_X))[idx] = f2bf(ws[OFS_G + n * 128 + k] * scX);
    } else if (idx < 36864) {
        int e = idx - 16384;                        // ATB [n=128][k=160] zero-pad
        int n = e / 160, k = e - n * 160;
        float v = (k < 144) ? ws[OFS_AF1 + n * 144 + k] * scA : 0.f;
        ((unsigned short*)(ws + OFS_ATB))[e] = f2bf(v);
    } else if (idx < 55296) {
        int e = idx - 36864;                        // ANTBP [jpix=144][ks=128]
        int jp = e >> 7, ks = e & 127;
        int g = ks >> 5, rem = ks & 31, u = rem >> 1, v = rem & 1;
        int n = g * 32 + v * 16 + u;                // pi^-1(ks)
        ((unsigned short*)(ws + OFS_ANTB))[e] = f2bf(ws[OFS_AF1 + n * 144 + jp] * scA);
    } else {
        int e = idx - 55296;                        // < 45056
        if (e < 45000) ws[OFS_GOAL + e] = y[e];
        if (e < 32768) {
            int b = e >> 12, pi = (e >> 6) & 63, pj = e & 63;
            const float* yb = y + b * 5625;
            float s = 0.f;
            for (int di = 0; di < 12; ++di) {
                const float* row = yb + (pi + di) * 75 + pj;
                #pragma unroll
                for (int dj = 0; dj < 12; ++dj) s += row[dj];
            }
            ws[OFS_PM + e] = s * (1.0f / 144.0f);
        }
    }
}

// ---- fused megakernel: q (im2col MFMA) + FISTA(15)+1 + pred.
//      Z stored column-interleaved: epilogue writes are paired b32. (R10 champion) ----
__global__ __launch_bounds__(256) void k_fista(const unsigned short* XPB, const float* goal,
                                               const unsigned short* ATB,
                                               const unsigned short* ANTBP,
                                               const float* pm, float* cfg, float* pred,
                                               const float* mu_p, int first, int write_cf) {
    __shared__ float gls[12 * 44];
    __shared__ unsigned short Atile[32 * 168];
    __shared__ unsigned short Zbuf[2][32 * 136];
    int t = threadIdx.x;
    int lane = t & 63, w = t >> 6;
    int col = lane & 15, quad = lane >> 4;
    int nb = w * 32;
    int blk = blockIdx.x;
    int b = blk >> 7, pi = (blk >> 1) & 63, h = blk & 1;
    int p0 = blk * 32;
    float mu = fmaxf(mu_p[0], 0.0f);

    // ---- stage goal slice (12 x 44, zero-pad past col 74) ----
    for (int e = t; e < 528; e += 256) {
        int r = e / 44, cc = e - r * 44;
        int gc = h * 32 + cc;
        gls[e] = (gc < 75) ? goal[b * 5625 + (pi + r) * 75 + gc] : 0.f;
    }
    __syncthreads();
    // ---- im2col A-tile 32 x 160 bf16, pair-packed b32 writes ----
    {
        uint32_t* A32 = (uint32_t*)Atile;          // row stride 84 u32
        #pragma unroll
        for (int i = 0; i < 10; ++i) {
            int pe = t + i * 256;                  // < 2560 = 32m * 80 pairs
            int m = pe / 80, q32 = pe - m * 80;
            int kk = q32 * 2;
            float v0 = 0.f, v1 = 0.f;
            if (kk < 144) {
                int di = kk / 12, dj = kk - di * 12;
                v0 = gls[di * 44 + m + dj];
                int k1 = kk + 1, di1 = k1 / 12, dj1 = k1 - di1 * 12;
                v1 = gls[di1 * 44 + m + dj1];
            }
            A32[m * 84 + q32] = pack_bf(v0, v1);
        }
    }
    __syncthreads();

    // ---- q-matmul: qv = im2col @ atoms^T (natural k-order), C/D layout ----
    float qv[2][2][4];
    {
        short8_t bfq[2][5];
        #pragma unroll
        for (int nt = 0; nt < 2; ++nt)
            #pragma unroll
            for (int s = 0; s < 5; ++s)
                bfq[nt][s] = *(const short8_t*)&ATB[(nb + nt * 16 + col) * 160 + s * 32 + quad * 8];
        #pragma unroll
        for (int mt = 0; mt < 2; ++mt) {
            short8_t af[5];
            #pragma unroll
            for (int s = 0; s < 5; ++s)
                af[s] = *(const short8_t*)&Atile[(mt * 16 + col) * 168 + s * 32 + quad * 8];
            f32x4 acc0 = (f32x4){0.f, 0.f, 0.f, 0.f};
            f32x4 acc1 = (f32x4){0.f, 0.f, 0.f, 0.f};
            #pragma unroll
            for (int s = 0; s < 5; ++s) {
                acc0 = __builtin_amdgcn_mfma_f32_16x16x32_bf16(af[s], bfq[0][s], acc0, 0, 0, 0);
                acc1 = __builtin_amdgcn_mfma_f32_16x16x32_bf16(af[s], bfq[1][s], acc1, 0, 0, 0);
            }
            #pragma unroll
            for (int r = 0; r < 4; ++r) { qv[mt][0][r] = acc0[r]; qv[mt][1][r] = acc1[r]; }
        }
    }

    // ---- X B-fragments: contiguous b128 from pre-permuted bf16 XPB ----
    short8_t xf[2][4];
    #pragma unroll
    for (int nt = 0; nt < 2; ++nt)
        #pragma unroll
        for (int s = 0; s < 4; ++s)
            xf[nt][s] = *(const short8_t*)&XPB[(nb + nt * 16 + col) * 128 + s * 32 + quad * 8];

    // ---- c0 / z0 init, seed Z (paired b32, interleaved cols) ----
    uint32_t* Z32w = (uint32_t*)Zbuf[0];           // row stride 68 u32
    float cv[2][2][4], zo[2][2][4];
    #pragma unroll
    for (int mt = 0; mt < 2; ++mt)
        #pragma unroll
        for (int r = 0; r < 4; ++r) {
            int row = mt * 16 + quad * 4 + r;
            int p = p0 + row;
            float c0 = 0.f, c1 = 0.f;
            if (!first) {
                c0 = cfg[p * 128 + nb + col];
                c1 = cfg[p * 128 + nb + 16 + col];
            }
            cv[mt][0][r] = c0; cv[mt][1][r] = c1;
            zo[mt][0][r] = c0; zo[mt][1][r] = c1;
            Z32w[row * 68 + 16 * w + col] = pack_bf(c0, c1);
        }
    __syncthreads();

    f32x4 acc[2][2];
    auto matmul = [&](const unsigned short* Zr) {
        short8_t af[2][4];
        #pragma unroll
        for (int mt = 0; mt < 2; ++mt)
            #pragma unroll
            for (int s = 0; s < 4; ++s)
                af[mt][s] = *(const short8_t*)&Zr[(mt * 16 + col) * 136 + s * 32 + quad * 8];
        #pragma unroll
        for (int mt = 0; mt < 2; ++mt)
            #pragma unroll
            for (int nt = 0; nt < 2; ++nt)
                acc[mt][nt] = (f32x4){0.f, 0.f, 0.f, 0.f};
        #pragma unroll
        for (int s = 0; s < 4; ++s)
            #pragma unroll
            for (int mt = 0; mt < 2; ++mt)
                #pragma unroll
                for (int nt = 0; nt < 2; ++nt)
                    acc[mt][nt] = __builtin_amdgcn_mfma_f32_16x16x32_bf16(
                        af[mt][s], xf[nt][s], acc[mt][nt], 0, 0, 0);
    };

    float tm = 1.0f;
    int cur = 0;
    #pragma unroll 1
    for (int it = 0; it < 14; ++it) {          // FISTA iters 1..14 (write z)
        matmul(Zbuf[cur]);
        float tnn = 0.5f * (1.0f + sqrtf(1.0f + 4.0f * tm * tm));
        float fm = (tm - 1.0f) / tnn;
        tm = tnn;
        uint32_t* Zw = (uint32_t*)Zbuf[cur ^ 1];
        #pragma unroll
        for (int mt = 0; mt < 2; ++mt)
            #pragma unroll
            for (int r = 0; r < 4; ++r) {
                float zn2[2];
                #pragma unroll
                for (int nt = 0; nt < 2; ++nt) {
                    float df = qv[mt][nt][r] - acc[mt][nt][r];
                    float u = fmaf(mu, df, zo[mt][nt][r]);
                    float cl = fminf(fmaxf(u, -LAM), LAM);
                    float cn = u - cl;
                    float d = cn - cv[mt][nt][r];
                    float zn = fmaf(fm, d, cn);
                    cv[mt][nt][r] = cn;
                    zo[mt][nt][r] = zn;
                    zn2[nt] = zn;
                }
                Zw[(mt * 16 + quad * 4 + r) * 68 + 16 * w + col] = pack_bf(zn2[0], zn2[1]);
            }
        __syncthreads();
        cur ^= 1;
    }
    {   // FISTA iter 15: compute c15; stage c15 (z15 never consumed)
        matmul(Zbuf[cur]);
        uint32_t* Zw = (uint32_t*)Zbuf[cur ^ 1];
        #pragma unroll
        for (int mt = 0; mt < 2; ++mt)
            #pragma unroll
            for (int r = 0; r < 4; ++r) {
                float cn2[2];
                #pragma unroll
                for (int nt = 0; nt < 2; ++nt) {
                    float df = qv[mt][nt][r] - acc[mt][nt][r];
                    float u = fmaf(mu, df, zo[mt][nt][r]);
                    float cl = fminf(fmaxf(u, -LAM), LAM);
                    float cn = u - cl;
                    cv[mt][nt][r] = cn;
                    cn2[nt] = cn;
                }
                Zw[(mt * 16 + quad * 4 + r) * 68 + 16 * w + col] = pack_bf(cn2[0], cn2[1]);
            }
        __syncthreads();
        cur ^= 1;
    }
    {   // final differentiable step: cf = prox(c15 + mu*(q - X@c15)); stage cf
        matmul(Zbuf[cur]);
        uint32_t* Zw = (uint32_t*)Zbuf[cur ^ 1];
        #pragma unroll
        for (int mt = 0; mt < 2; ++mt)
            #pragma unroll
            for (int r = 0; r < 4; ++r) {
                int row = mt * 16 + quad * 4 + r;
                float cf2[2];
                #pragma unroll
                for (int nt = 0; nt < 2; ++nt) {
                    float df = qv[mt][nt][r] - acc[mt][nt][r];
                    float u = fmaf(mu, df, cv[mt][nt][r]);
                    float cl = fminf(fmaxf(u, -LAM), LAM);
                    float cf = u - cl;
                    if (write_cf)
                        cfg[(p0 + row) * 128 + nb + nt * 16 + col] = cf;
                    cf2[nt] = cf;
                }
                Zw[row * 68 + 16 * w + col] = pack_bf(cf2[0], cf2[1]);
            }
        __syncthreads();
        cur ^= 1;
    }

    // ---- pred tail: pred[32][144] = cf @ atoms_n + pm (B pre-permuted ANTBP) ----
    {
        int jt0 = (w == 0) ? 0 : (2 * w + 1);
        int jtn = (w == 0) ? 3 : 2;
        const unsigned short* Zr = Zbuf[cur];
        short8_t af[2][4];
        #pragma unroll
        for (int mt = 0; mt < 2; ++mt)
            #pragma unroll
            for (int s = 0; s < 4; ++s)
                af[mt][s] = *(const short8_t*)&Zr[(mt * 16 + col) * 136 + s * 32 + quad * 8];
        f32x4 accp[2][3];
        #pragma unroll
        for (int mt = 0; mt < 2; ++mt)
            #pragma unroll
            for (int ji = 0; ji < 3; ++ji)
                accp[mt][ji] = (f32x4){0.f, 0.f, 0.f, 0.f};
        #pragma unroll
        for (int ji = 0; ji < 3; ++ji) {
            if (ji < jtn) {
                int jt = jt0 + ji;
                short8_t bf4[4];
                #pragma unroll
                for (int s = 0; s < 4; ++s)
                    bf4[s] = *(const short8_t*)&ANTBP[(jt * 16 + col) * 128 + s * 32 + quad * 8];
                #pragma unroll
                for (int mt = 0; mt < 2; ++mt)
                    #pragma unroll
                    for (int s = 0; s < 4; ++s)
                        accp[mt][ji] = __builtin_amdgcn_mfma_f32_16x16x32_bf16(
                            af[mt][s], bf4[s], accp[mt][ji], 0, 0, 0);
            }
        }
        #pragma unroll
        for (int mt = 0; mt < 2; ++mt)
            #pragma unroll
            for (int r = 0; r < 4; ++r) {
                int p = p0 + mt * 16 + quad * 4 + r;
                float pmv = pm[p];
                #pragma unroll
                for (int ji = 0; ji < 3; ++ji)
                    if (ji < jtn)
                        pred[p * 144 + (jt0 + ji) * 16 + col] = accp[mt][ji][r] + pmv;
            }
    }
}

// ---- fold via LDS staging: block = (output row i, batch b); coalesced pred reads. ----
__global__ __launch_bounds__(256) void k_fold(const float* y, const float* beta_p,
                                              const float* pred, float* goal,
                                              float* out, int write_out) {
    __shared__ float P[12 * 832];              // 39,936 B
    int i = blockIdx.x, b = blockIdx.y;
    int t = threadIdx.x;
    for (int di = 0; di < 12; ++di) {
        int pi = i - di;
        if ((unsigned)pi >= 64u) continue;     // uniform per block
        int base = (b << 12) + (pi << 6);
        #pragma unroll
        for (int it = 0; it < 3; ++it) {
            int e = t + it * 256;              // < 768 = 64 pj * 12 dj
            int pj = e / 12, dj = e - pj * 12;
            P[di * 832 + pj * 13 + dj] = pred[(base + pj) * AA + di * 12 + dj];
        }
    }
    __syncthreads();
    if (t >= 75) return;
    int j = t;
    float S = 0.f;
    for (int di = 0; di < 12; ++di) {
        if ((unsigned)(i - di) >= 64u) continue;
        const float* Pd = &P[di * 832];
        #pragma unroll
        for (int dj = 0; dj < 12; ++dj) {
            int pj = j - dj;
            if ((unsigned)pj >= 64u) continue;
            S += Pd[pj * 13 + dj];
        }
    }
    int ci = min(i, 11) - max(i - 63, 0) + 1;
    int cj = min(j, 11) - max(j - 63, 0) + 1;
    float beta = fmaxf(beta_p[0], 0.0f);
    int idx = i * 75 + j;
    float yv = y[b * 5625 + idx];
    float g = (yv + beta * S) / (1.0f + beta * (float)(ci * cj));
    if (write_out) out[b * 5625 + idx] = g;
    else           goal[b * 5625 + idx] = g;
}

extern "C" void kernel_launch(void* const* d_in, const int* in_sizes, int n_in,
                              void* d_out, int out_size, void* d_ws, size_t ws_size,
                              hipStream_t stream) {
    const float* y     = (const float*)d_in[0];
    const float* atoms = (const float*)d_in[1];
    const float* beta  = (const float*)d_in[2];
    const float* mu    = (const float*)d_in[3];
    float* out = (float*)d_out;
    float* ws = (float*)d_ws;

    k_setup<<<1, 256, 0, stream>>>(atoms, mu, ws);  // norm + gram + power + Rayleigh
    k_finalize<<<392, 256, 0, stream>>>(ws, y);     // XPB + ATB + ANTBP + goal + pm

    for (int u = 0; u < 2; ++u) {
        k_fista<<<1024, 256, 0, stream>>>((const unsigned short*)(ws + OFS_X),
                                          ws + OFS_GOAL,
                                          (const unsigned short*)(ws + OFS_ATB),
                                          (const unsigned short*)(ws + OFS_ANTB),
                                          ws + OFS_PM, ws + OFS_CF, ws + OFS_PRED,
                                          mu, u == 0 ? 1 : 0, u == 0 ? 1 : 0);
        k_fold<<<dim3(75, 8), 256, 0, stream>>>(y, beta, ws + OFS_PRED,
                                                ws + OFS_GOAL, out, u == 1 ? 1 : 0);
    }
}

// Round 14
// 223.969 us; speedup vs baseline: 1.2812x; 1.1211x over previous
//
#include <hip/hip_runtime.h>
#include <stdint.h>

// Problem constants
#define AA 144          // ATOM*ATOM
#define LAM 0.1f

// ---- workspace layout (float offsets) ----
#define OFS_SC    0            // 64 scalars: [16]=scX, [17]=scA
#define OFS_AF1   64           // 128*144 row-normalized zero-mean atoms
#define OFS_G     36928        // 128*128 gram (f32)
#define OFS_S0    53312        // ATB (bf16 atoms, [128][160] u16)
#define OFS_S1    69696        // ANTBP (bf16 atomsT, n-permuted, [144][128] u16)
#define OFS_X     86080        // XPB: bf16 X, k-permuted, [128][128] u16
#define OFS_PM    139328       // 32768 patch means
#define OFS_GOAL  172096       // 45056 goal (f32)
#define OFS_CF    4411456      // 32768*128
#define OFS_PRED  8605760      // 32768*144
#define OFS_ATB   OFS_S0
#define OFS_ANTB  OFS_S1

// Contraction-dim permutation: real n = 32g + 16v + u  <->  stored ks = 32g + 2u + v.
// A and B sides both use stored order -> dot products unchanged.

typedef __attribute__((ext_vector_type(8))) short short8_t;
typedef __attribute__((ext_vector_type(4))) float f32x4;

__device__ __forceinline__ unsigned short f2bf(float f) {      // RNE
    union { float f; uint32_t u; } x; x.f = f;
    uint32_t u = x.u;
    return (unsigned short)((u + 0x7FFFu + ((u >> 16) & 1u)) >> 16);
}
__device__ __forceinline__ float bf2f(unsigned short u) {
    union { float f; uint32_t i; } x; x.i = ((uint32_t)u) << 16; return x.f;
}
// pack two f32 -> packed bf16 pair (a->low, b->high), round-half-up
__device__ __forceinline__ uint32_t pack_bf(float a, float b) {
    union { float f; uint32_t u; } xa, xb; xa.f = a; xb.f = b;
    return __builtin_amdgcn_perm(xb.u + 0x8000u, xa.u + 0x8000u, 0x07060302u);
}

// ---- fused setup, 1024 threads (16 waves, 4/SIMD — R13 was 4 waves total):
//      atom norm -> bf16 gram (MFMA) -> 8x power squarings -> Rayleigh. ----
#define PSTR 136
__global__ __launch_bounds__(1024) void k_setup(const float* atoms, const float* mu_p,
                                                float* ws) {
    __shared__ unsigned short ABf[128 * 168];       // 43008 B
    __shared__ unsigned short Pb[2][128 * PSTR];    // 69632 B
    __shared__ float tr_arr[10];
    __shared__ float v[128];
    __shared__ float red[256];
    int t = threadIdx.x;
    int lane = t & 63, w = t >> 6;
    int col = lane & 15, quad = lane >> 4;
    if (t < 10) tr_arr[t] = (t == 0) ? 128.0f : 0.f;

    // ---- norm: 8 threads/atom, width-8 shfl reductions ----
    {
        int a = t >> 3, sub = t & 7;               // 128 atoms x 8 subs
        const float* ap = atoms + a * AA + sub * 18;
        float s = 0.f;
        #pragma unroll
        for (int k = 0; k < 18; ++k) s += ap[k];
        s += __shfl_xor(s, 1, 8); s += __shfl_xor(s, 2, 8); s += __shfl_xor(s, 4, 8);
        float mean = s * (1.0f / 144.0f);
        float ss = 0.f;
        #pragma unroll
        for (int k = 0; k < 18; ++k) { float d = ap[k] - mean; ss = fmaf(d, d, ss); }
        ss += __shfl_xor(ss, 1, 8); ss += __shfl_xor(ss, 2, 8); ss += __shfl_xor(ss, 4, 8);
        float rn = 1.0f / sqrtf(ss);
        #pragma unroll
        for (int k = 0; k < 18; ++k) {
            float av = (ap[k] - mean) * rn;
            ws[OFS_AF1 + a * AA + sub * 18 + k] = av;
            ABf[a * 168 + sub * 18 + k] = f2bf(av);
        }
        if (sub == 0) {
            #pragma unroll
            for (int k = AA; k < 160; ++k) ABf[a * 168 + k] = 0;
        }
    }
    __syncthreads();

    // ---- gram: wave w -> m-tile (w&7), g-half (w>>3). Same tile math as R13. ----
    {
        uint32_t* D32 = (uint32_t*)Pb[0];           // row stride 68 u32 (permuted cols)
        float* G = ws + OFS_G;
        int mt = w & 7, gh = w >> 3;
        short8_t af[5];
        #pragma unroll
        for (int s = 0; s < 5; ++s)
            af[s] = *(const short8_t*)&ABf[(mt * 16 + col) * 168 + s * 32 + quad * 8];
        #pragma unroll
        for (int gi = 0; gi < 2; ++gi) {
            int g = gh * 2 + gi;
            short8_t b0[5], b1[5];
            #pragma unroll
            for (int s = 0; s < 5; ++s) {
                b0[s] = *(const short8_t*)&ABf[((2 * g) * 16 + col) * 168 + s * 32 + quad * 8];
                b1[s] = *(const short8_t*)&ABf[((2 * g + 1) * 16 + col) * 168 + s * 32 + quad * 8];
            }
            f32x4 a0 = (f32x4){0.f, 0.f, 0.f, 0.f};
            f32x4 a1 = (f32x4){0.f, 0.f, 0.f, 0.f};
            #pragma unroll
            for (int s = 0; s < 5; ++s) {
                a0 = __builtin_amdgcn_mfma_f32_16x16x32_bf16(af[s], b0[s], a0, 0, 0, 0);
                a1 = __builtin_amdgcn_mfma_f32_16x16x32_bf16(af[s], b1[s], a1, 0, 0, 0);
            }
            #pragma unroll
            for (int r = 0; r < 4; ++r) {
                int m = mt * 16 + quad * 4 + r;
                G[m * 128 + g * 32 + col] = a0[r];
                G[m * 128 + g * 32 + 16 + col] = a1[r];
                D32[m * 68 + g * 16 + col] = pack_bf(a0[r], a1[r]);
            }
        }
    }
    __syncthreads();

    // ---- power: 8 squarings; wave w -> m-tile (w&7), n-quarter (w>>3) ----
    int cur = 0;
    #pragma unroll 1
    for (int j = 0; j < 8; ++j) {
        float trn = tr_arr[j];
        float inv2 = 1.0f / (trn * trn);
        const unsigned short* S = Pb[cur];
        uint32_t* D32 = (uint32_t*)Pb[cur ^ 1];     // row stride 68 u32
        int mt = w & 7, nh = w >> 3;
        short8_t af[4];
        #pragma unroll
        for (int s = 0; s < 4; ++s)
            af[s] = *(const short8_t*)&S[(mt * 16 + col) * PSTR + s * 32 + quad * 8];
        #pragma unroll
        for (int pr = 0; pr < 2; ++pr) {
            int ntE = 4 * nh + 2 * pr, ntO = ntE + 1;
            short8_t bE[4], bO[4];
            #pragma unroll
            for (int s = 0; s < 4; ++s) {
                bE[s] = *(const short8_t*)&S[(ntE * 16 + col) * PSTR + s * 32 + quad * 8];
                bO[s] = *(const short8_t*)&S[(ntO * 16 + col) * PSTR + s * 32 + quad * 8];
            }
            f32x4 aE = (f32x4){0.f, 0.f, 0.f, 0.f};
            f32x4 aO = (f32x4){0.f, 0.f, 0.f, 0.f};
            #pragma unroll
            for (int s = 0; s < 4; ++s) {
                aE = __builtin_amdgcn_mfma_f32_16x16x32_bf16(af[s], bE[s], aE, 0, 0, 0);
                aO = __builtin_amdgcn_mfma_f32_16x16x32_bf16(af[s], bO[s], aO, 0, 0, 0);
            }
            int nE = ntE * 16 + col, nO = ntO * 16 + col;
            #pragma unroll
            for (int r = 0; r < 4; ++r) {
                float x0 = aE[r] * inv2, x1 = aO[r] * inv2;
                int row = mt * 16 + quad * 4 + r;
                D32[row * 68 + (ntE >> 1) * 16 + col] = pack_bf(x0, x1);
                if (row == nE) atomicAdd(&tr_arr[j + 1], x0);
                if (row == nO) atomicAdd(&tr_arr[j + 1], x1);
            }
        }
        __syncthreads();
        cur ^= 1;
    }

    // ---- Rayleigh on f32 G: v = P*ones; lam = v'Gv / v'v (8 threads/row) ----
    {
        int a = t >> 3, sub = t & 7;
        const unsigned short* S = Pb[cur];
        float s = 0.f;
        #pragma unroll
        for (int k = 0; k < 16; ++k) s += bf2f(S[a * PSTR + sub * 16 + k]);
        s += __shfl_xor(s, 1, 8); s += __shfl_xor(s, 2, 8); s += __shfl_xor(s, 4, 8);
        if (sub == 0) v[a] = s;
    }
    __syncthreads();
    {
        int a = t >> 3, sub = t & 7;
        const float* G = ws + OFS_G;
        float wv = 0.f;
        #pragma unroll
        for (int k = 0; k < 16; ++k)
            wv = fmaf(G[a * 128 + sub * 16 + k], v[sub * 16 + k], wv);
        wv += __shfl_xor(wv, 1, 8); wv += __shfl_xor(wv, 2, 8); wv += __shfl_xor(wv, 4, 8);
        if (sub == 0) { red[a] = v[a] * wv; red[128 + a] = v[a] * v[a]; }
    }
    __syncthreads();
    for (int off = 64; off > 0; off >>= 1) {
        if (t < off) { red[t] += red[t + off]; red[128 + t] += red[128 + t + off]; }
        __syncthreads();
    }
    if (t == 0) {
        float lam = red[0] / red[128];               // sigma^2 = lammax(G)
        float mu = fmaxf(mu_p[0], 0.0f);
        ws[OFS_SC + 16] = 1.0f / (lam * mu);                  // X scale
        ws[OFS_SC + 17] = 1.0f / (sqrtf(lam) * sqrtf(mu));    // atom scale
    }
}

// ---- finalize: XPB (bf16, k-permuted) ; ATB ; ANTBP (n-permuted) ; goal ; pm ----
__global__ __launch_bounds__(256) void k_finalize(float* ws, const float* y) {
    int idx = blockIdx.x * 256 + threadIdx.x;       // grid 392 -> 100352
    float scX = ws[OFS_SC + 16], scA = ws[OFS_SC + 17];
    if (idx < 16384) {
        int n = idx >> 7, ks = idx & 127;
        int g = ks >> 5, rem = ks & 31, u = rem >> 1, v = rem & 1;
        int k = g * 32 + v * 16 + u;                // pi^-1(ks)
        ((unsigned short*)(ws + OFS_X))[idx] = f2bf(ws[OFS_G + n * 128 + k] * scX);
    } else if (idx < 36864) {
        int e = idx - 16384;                        // ATB [n=128][k=160] zero-pad
        int n = e / 160, k = e - n * 160;
        float v = (k < 144) ? ws[OFS_AF1 + n * 144 + k] * scA : 0.f;
        ((unsigned short*)(ws + OFS_ATB))[e] = f2bf(v);
    } else if (idx < 55296) {
        int e = idx - 36864;                        // ANTBP [jpix=144][ks=128]
        int jp = e >> 7, ks = e & 127;
        int g = ks >> 5, rem = ks & 31, u = rem >> 1, v = rem & 1;
        int n = g * 32 + v * 16 + u;                // pi^-1(ks)
        ((unsigned short*)(ws + OFS_ANTB))[e] = f2bf(ws[OFS_AF1 + n * 144 + jp] * scA);
    } else {
        int e = idx - 55296;                        // < 45056
        if (e < 45000) ws[OFS_GOAL + e] = y[e];
        if (e < 32768) {
            int b = e >> 12, pi = (e >> 6) & 63, pj = e & 63;
            const float* yb = y + b * 5625;
            float s = 0.f;
            for (int di = 0; di < 12; ++di) {
                const float* row = yb + (pi + di) * 75 + pj;
                #pragma unroll
                for (int dj = 0; dj < 12; ++dj) s += row[dj];
            }
            ws[OFS_PM + e] = s * (1.0f / 144.0f);
        }
    }
}

// ---- fused megakernel: q (im2col MFMA) + FISTA(15)+1 + pred.
//      Z stored column-interleaved: epilogue writes are paired b32. (R10 champion) ----
__global__ __launch_bounds__(256) void k_fista(const unsigned short* XPB, const float* goal,
                                               const unsigned short* ATB,
                                               const unsigned short* ANTBP,
                                               const float* pm, float* cfg, float* pred,
                                               const float* mu_p, int first, int write_cf) {
    __shared__ float gls[12 * 44];
    __shared__ unsigned short Atile[32 * 168];
    __shared__ unsigned short Zbuf[2][32 * 136];
    int t = threadIdx.x;
    int lane = t & 63, w = t >> 6;
    int col = lane & 15, quad = lane >> 4;
    int nb = w * 32;
    int blk = blockIdx.x;
    int b = blk >> 7, pi = (blk >> 1) & 63, h = blk & 1;
    int p0 = blk * 32;
    float mu = fmaxf(mu_p[0], 0.0f);

    // ---- stage goal slice (12 x 44, zero-pad past col 74) ----
    for (int e = t; e < 528; e += 256) {
        int r = e / 44, cc = e - r * 44;
        int gc = h * 32 + cc;
        gls[e] = (gc < 75) ? goal[b * 5625 + (pi + r) * 75 + gc] : 0.f;
    }
    __syncthreads();
    // ---- im2col A-tile 32 x 160 bf16, pair-packed b32 writes ----
    {
        uint32_t* A32 = (uint32_t*)Atile;          // row stride 84 u32
        #pragma unroll
        for (int i = 0; i < 10; ++i) {
            int pe = t + i * 256;                  // < 2560 = 32m * 80 pairs
            int m = pe / 80, q32 = pe - m * 80;
            int kk = q32 * 2;
            float v0 = 0.f, v1 = 0.f;
            if (kk < 144) {
                int di = kk / 12, dj = kk - di * 12;
                v0 = gls[di * 44 + m + dj];
                int k1 = kk + 1, di1 = k1 / 12, dj1 = k1 - di1 * 12;
                v1 = gls[di1 * 44 + m + dj1];
            }
            A32[m * 84 + q32] = pack_bf(v0, v1);
        }
    }
    __syncthreads();

    // ---- q-matmul: qv = im2col @ atoms^T (natural k-order), C/D layout ----
    float qv[2][2][4];
    {
        short8_t bfq[2][5];
        #pragma unroll
        for (int nt = 0; nt < 2; ++nt)
            #pragma unroll
            for (int s = 0; s < 5; ++s)
                bfq[nt][s] = *(const short8_t*)&ATB[(nb + nt * 16 + col) * 160 + s * 32 + quad * 8];
        #pragma unroll
        for (int mt = 0; mt < 2; ++mt) {
            short8_t af[5];
            #pragma unroll
            for (int s = 0; s < 5; ++s)
                af[s] = *(const short8_t*)&Atile[(mt * 16 + col) * 168 + s * 32 + quad * 8];
            f32x4 acc0 = (f32x4){0.f, 0.f, 0.f, 0.f};
            f32x4 acc1 = (f32x4){0.f, 0.f, 0.f, 0.f};
            #pragma unroll
            for (int s = 0; s < 5; ++s) {
                acc0 = __builtin_amdgcn_mfma_f32_16x16x32_bf16(af[s], bfq[0][s], acc0, 0, 0, 0);
                acc1 = __builtin_amdgcn_mfma_f32_16x16x32_bf16(af[s], bfq[1][s], acc1, 0, 0, 0);
            }
            #pragma unroll
            for (int r = 0; r < 4; ++r) { qv[mt][0][r] = acc0[r]; qv[mt][1][r] = acc1[r]; }
        }
    }

    // ---- X B-fragments: contiguous b128 from pre-permuted bf16 XPB ----
    short8_t xf[2][4];
    #pragma unroll
    for (int nt = 0; nt < 2; ++nt)
        #pragma unroll
        for (int s = 0; s < 4; ++s)
            xf[nt][s] = *(const short8_t*)&XPB[(nb + nt * 16 + col) * 128 + s * 32 + quad * 8];

    // ---- c0 / z0 init, seed Z (paired b32, interleaved cols) ----
    uint32_t* Z32w = (uint32_t*)Zbuf[0];           // row stride 68 u32
    float cv[2][2][4], zo[2][2][4];
    #pragma unroll
    for (int mt = 0; mt < 2; ++mt)
        #pragma unroll
        for (int r = 0; r < 4; ++r) {
            int row = mt * 16 + quad * 4 + r;
            int p = p0 + row;
            float c0 = 0.f, c1 = 0.f;
            if (!first) {
                c0 = cfg[p * 128 + nb + col];
                c1 = cfg[p * 128 + nb + 16 + col];
            }
            cv[mt][0][r] = c0; cv[mt][1][r] = c1;
            zo[mt][0][r] = c0; zo[mt][1][r] = c1;
            Z32w[row * 68 + 16 * w + col] = pack_bf(c0, c1);
        }
    __syncthreads();

    f32x4 acc[2][2];
    auto matmul = [&](const unsigned short* Zr) {
        short8_t af[2][4];
        #pragma unroll
        for (int mt = 0; mt < 2; ++mt)
            #pragma unroll
            for (int s = 0; s < 4; ++s)
                af[mt][s] = *(const short8_t*)&Zr[(mt * 16 + col) * 136 + s * 32 + quad * 8];
        #pragma unroll
        for (int mt = 0; mt < 2; ++mt)
            #pragma unroll
            for (int nt = 0; nt < 2; ++nt)
                acc[mt][nt] = (f32x4){0.f, 0.f, 0.f, 0.f};
        #pragma unroll
        for (int s = 0; s < 4; ++s)
            #pragma unroll
            for (int mt = 0; mt < 2; ++mt)
                #pragma unroll
                for (int nt = 0; nt < 2; ++nt)
                    acc[mt][nt] = __builtin_amdgcn_mfma_f32_16x16x32_bf16(
                        af[mt][s], xf[nt][s], acc[mt][nt], 0, 0, 0);
    };

    float tm = 1.0f;
    int cur = 0;
    #pragma unroll 1
    for (int it = 0; it < 14; ++it) {          // FISTA iters 1..14 (write z)
        matmul(Zbuf[cur]);
        float tnn = 0.5f * (1.0f + sqrtf(1.0f + 4.0f * tm * tm));
        float fm = (tm - 1.0f) / tnn;
        tm = tnn;
        uint32_t* Zw = (uint32_t*)Zbuf[cur ^ 1];
        #pragma unroll
        for (int mt = 0; mt < 2; ++mt)
            #pragma unroll
            for (int r = 0; r < 4; ++r) {
                float zn2[2];
                #pragma unroll
                for (int nt = 0; nt < 2; ++nt) {
                    float df = qv[mt][nt][r] - acc[mt][nt][r];
                    float u = fmaf(mu, df, zo[mt][nt][r]);
                    float cl = fminf(fmaxf(u, -LAM), LAM);
                    float cn = u - cl;
                    float d = cn - cv[mt][nt][r];
                    float zn = fmaf(fm, d, cn);
                    cv[mt][nt][r] = cn;
                    zo[mt][nt][r] = zn;
                    zn2[nt] = zn;
                }
                Zw[(mt * 16 + quad * 4 + r) * 68 + 16 * w + col] = pack_bf(zn2[0], zn2[1]);
            }
        __syncthreads();
        cur ^= 1;
    }
    {   // FISTA iter 15: compute c15; stage c15 (z15 never consumed)
        matmul(Zbuf[cur]);
        uint32_t* Zw = (uint32_t*)Zbuf[cur ^ 1];
        #pragma unroll
        for (int mt = 0; mt < 2; ++mt)
            #pragma unroll
            for (int r = 0; r < 4; ++r) {
                float cn2[2];
                #pragma unroll
                for (int nt = 0; nt < 2; ++nt) {
                    float df = qv[mt][nt][r] - acc[mt][nt][r];
                    float u = fmaf(mu, df, zo[mt][nt][r]);
                    float cl = fminf(fmaxf(u, -LAM), LAM);
                    float cn = u - cl;
                    cv[mt][nt][r] = cn;
                    cn2[nt] = cn;
                }
                Zw[(mt * 16 + quad * 4 + r) * 68 + 16 * w + col] = pack_bf(cn2[0], cn2[1]);
            }
        __syncthreads();
        cur ^= 1;
    }
    {   // final differentiable step: cf = prox(c15 + mu*(q - X@c15)); stage cf
        matmul(Zbuf[cur]);
        uint32_t* Zw = (uint32_t*)Zbuf[cur ^ 1];
        #pragma unroll
        for (int mt = 0; mt < 2; ++mt)
            #pragma unroll
            for (int r = 0; r < 4; ++r) {
                int row = mt * 16 + quad * 4 + r;
                float cf2[2];
                #pragma unroll
                for (int nt = 0; nt < 2; ++nt) {
                    float df = qv[mt][nt][r] - acc[mt][nt][r];
                    float u = fmaf(mu, df, cv[mt][nt][r]);
                    float cl = fminf(fmaxf(u, -LAM), LAM);
                    float cf = u - cl;
                    if (write_cf)
                        cfg[(p0 + row) * 128 + nb + nt * 16 + col] = cf;
                    cf2[nt] = cf;
                }
                Zw[row * 68 + 16 * w + col] = pack_bf(cf2[0], cf2[1]);
            }
        __syncthreads();
        cur ^= 1;
    }

    // ---- pred tail: pred[32][144] = cf @ atoms_n + pm (B pre-permuted ANTBP) ----
    {
        int jt0 = (w == 0) ? 0 : (2 * w + 1);
        int jtn = (w == 0) ? 3 : 2;
        const unsigned short* Zr = Zbuf[cur];
        short8_t af[2][4];
        #pragma unroll
        for (int mt = 0; mt < 2; ++mt)
            #pragma unroll
            for (int s = 0; s < 4; ++s)
                af[mt][s] = *(const short8_t*)&Zr[(mt * 16 + col) * 136 + s * 32 + quad * 8];
        f32x4 accp[2][3];
        #pragma unroll
        for (int mt = 0; mt < 2; ++mt)
            #pragma unroll
            for (int ji = 0; ji < 3; ++ji)
                accp[mt][ji] = (f32x4){0.f, 0.f, 0.f, 0.f};
        #pragma unroll
        for (int ji = 0; ji < 3; ++ji) {
            if (ji < jtn) {
                int jt = jt0 + ji;
                short8_t bf4[4];
                #pragma unroll
                for (int s = 0; s < 4; ++s)
                    bf4[s] = *(const short8_t*)&ANTBP[(jt * 16 + col) * 128 + s * 32 + quad * 8];
                #pragma unroll
                for (int mt = 0; mt < 2; ++mt)
                    #pragma unroll
                    for (int s = 0; s < 4; ++s)
                        accp[mt][ji] = __builtin_amdgcn_mfma_f32_16x16x32_bf16(
                            af[mt][s], bf4[s], accp[mt][ji], 0, 0, 0);
            }
        }
        #pragma unroll
        for (int mt = 0; mt < 2; ++mt)
            #pragma unroll
            for (int r = 0; r < 4; ++r) {
                int p = p0 + mt * 16 + quad * 4 + r;
                float pmv = pm[p];
                #pragma unroll
                for (int ji = 0; ji < 3; ++ji)
                    if (ji < jtn)
                        pred[p * 144 + (jt0 + ji) * 16 + col] = accp[mt][ji][r] + pmv;
            }
    }
}

// ---- fold via LDS staging: block = (output row i, batch b); coalesced pred reads. ----
__global__ __launch_bounds__(256) void k_fold(const float* y, const float* beta_p,
                                              const float* pred, float* goal,
                                              float* out, int write_out) {
    __shared__ float P[12 * 832];              // 39,936 B
    int i = blockIdx.x, b = blockIdx.y;
    int t = threadIdx.x;
    for (int di = 0; di < 12; ++di) {
        int pi = i - di;
        if ((unsigned)pi >= 64u) continue;     // uniform per block
        int base = (b << 12) + (pi << 6);
        #pragma unroll
        for (int it = 0; it < 3; ++it) {
            int e = t + it * 256;              // < 768 = 64 pj * 12 dj
            int pj = e / 12, dj = e - pj * 12;
            P[di * 832 + pj * 13 + dj] = pred[(base + pj) * AA + di * 12 + dj];
        }
    }
    __syncthreads();
    if (t >= 75) return;
    int j = t;
    float S = 0.f;
    for (int di = 0; di < 12; ++di) {
        if ((unsigned)(i - di) >= 64u) continue;
        const float* Pd = &P[di * 832];
        #pragma unroll
        for (int dj = 0; dj < 12; ++dj) {
            int pj = j - dj;
            if ((unsigned)pj >= 64u) continue;
            S += Pd[pj * 13 + dj];
        }
    }
    int ci = min(i, 11) - max(i - 63, 0) + 1;
    int cj = min(j, 11) - max(j - 63, 0) + 1;
    float beta = fmaxf(beta_p[0], 0.0f);
    int idx = i * 75 + j;
    float yv = y[b * 5625 + idx];
    float g = (yv + beta * S) / (1.0f + beta * (float)(ci * cj));
    if (write_out) out[b * 5625 + idx] = g;
    else           goal[b * 5625 + idx] = g;
}

extern "C" void kernel_launch(void* const* d_in, const int* in_sizes, int n_in,
                              void* d_out, int out_size, void* d_ws, size_t ws_size,
                              hipStream_t stream) {
    const float* y     = (const float*)d_in[0];
    const float* atoms = (const float*)d_in[1];
    const float* beta  = (const float*)d_in[2];
    const float* mu    = (const float*)d_in[3];
    float* out = (float*)d_out;
    float* ws = (float*)d_ws;

    k_setup<<<1, 1024, 0, stream>>>(atoms, mu, ws); // norm + gram + power + Rayleigh
    k_finalize<<<392, 256, 0, stream>>>(ws, y);     // XPB + ATB + ANTBP + goal + pm

    for (int u = 0; u < 2; ++u) {
        k_fista<<<1024, 256, 0, stream>>>((const unsigned short*)(ws + OFS_X),
                                          ws + OFS_GOAL,
                                          (const unsigned short*)(ws + OFS_ATB),
                                          (const unsigned short*)(ws + OFS_ANTB),
                                          ws + OFS_PM, ws + OFS_CF, ws + OFS_PRED,
                                          mu, u == 0 ? 1 : 0, u == 0 ? 1 : 0);
        k_fold<<<dim3(75, 8), 256, 0, stream>>>(y, beta, ws + OFS_PRED,
                                                ws + OFS_GOAL, out, u == 1 ? 1 : 0);
    }
}

// Round 15
// 215.712 us; speedup vs baseline: 1.3302x; 1.0383x over previous
//
#include <hip/hip_runtime.h>
#include <stdint.h>

// Problem constants
#define AA 144          // ATOM*ATOM
#define LAM 0.1f

// ---- workspace layout (float offsets) ----
#define OFS_SC    0            // 64 scalars: [16]=scX, [17]=scA
#define OFS_AF1   64           // 128*144 row-normalized zero-mean atoms
#define OFS_G     36928        // 128*128 gram (f32)
#define OFS_S0    53312        // ATB (bf16 atoms, [128][160] u16)
#define OFS_S1    69696        // ANTBP (bf16 atomsT, n-permuted, [144][128] u16)
#define OFS_X     86080        // XPB: bf16 X, k-permuted, [128][128] u16
#define OFS_PM    139328       // 32768 patch means
#define OFS_GOAL  172096       // 45056 goal (f32)
#define OFS_CF    4411456      // 32768*128
#define OFS_PRED  8605760      // 32768*144
#define OFS_ATB   OFS_S0
#define OFS_ANTB  OFS_S1

// Contraction-dim permutation: real n = 32g + 16v + u  <->  stored ks = 32g + 2u + v.
// A and B sides both use stored order -> dot products unchanged.

typedef __attribute__((ext_vector_type(8))) short short8_t;
typedef __attribute__((ext_vector_type(4))) float f32x4;
typedef __attribute__((ext_vector_type(2))) float f32x2;

__device__ __forceinline__ unsigned short f2bf(float f) {      // RNE
    union { float f; uint32_t u; } x; x.f = f;
    uint32_t u = x.u;
    return (unsigned short)((u + 0x7FFFu + ((u >> 16) & 1u)) >> 16);
}
__device__ __forceinline__ float bf2f(unsigned short u) {
    union { float f; uint32_t i; } x; x.i = ((uint32_t)u) << 16; return x.f;
}
// pack two f32 -> packed bf16 pair (a->low, b->high), round-half-up
__device__ __forceinline__ uint32_t pack_bf(float a, float b) {
    union { float f; uint32_t u; } xa, xb; xa.f = a; xb.f = b;
    return __builtin_amdgcn_perm(xb.u + 0x8000u, xa.u + 0x8000u, 0x07060302u);
}

// ---- fused setup, 1024 threads (16 waves):
//      atom norm -> bf16 gram (MFMA) -> 8x power squarings -> Rayleigh. ----
#define PSTR 136
__global__ __launch_bounds__(1024) void k_setup(const float* atoms, const float* mu_p,
                                                float* ws) {
    __shared__ unsigned short ABf[128 * 168];       // 43008 B
    __shared__ unsigned short Pb[2][128 * PSTR];    // 69632 B
    __shared__ float tr_arr[10];
    __shared__ float v[128];
    __shared__ float red[256];
    int t = threadIdx.x;
    int lane = t & 63, w = t >> 6;
    int col = lane & 15, quad = lane >> 4;
    if (t < 10) tr_arr[t] = (t == 0) ? 128.0f : 0.f;

    // ---- norm: 8 threads/atom, width-8 shfl reductions ----
    {
        int a = t >> 3, sub = t & 7;               // 128 atoms x 8 subs
        const float* ap = atoms + a * AA + sub * 18;
        float s = 0.f;
        #pragma unroll
        for (int k = 0; k < 18; ++k) s += ap[k];
        s += __shfl_xor(s, 1, 8); s += __shfl_xor(s, 2, 8); s += __shfl_xor(s, 4, 8);
        float mean = s * (1.0f / 144.0f);
        float ss = 0.f;
        #pragma unroll
        for (int k = 0; k < 18; ++k) { float d = ap[k] - mean; ss = fmaf(d, d, ss); }
        ss += __shfl_xor(ss, 1, 8); ss += __shfl_xor(ss, 2, 8); ss += __shfl_xor(ss, 4, 8);
        float rn = 1.0f / sqrtf(ss);
        #pragma unroll
        for (int k = 0; k < 18; ++k) {
            float av = (ap[k] - mean) * rn;
            ws[OFS_AF1 + a * AA + sub * 18 + k] = av;
            ABf[a * 168 + sub * 18 + k] = f2bf(av);
        }
        if (sub == 0) {
            #pragma unroll
            for (int k = AA; k < 160; ++k) ABf[a * 168 + k] = 0;
        }
    }
    __syncthreads();

    // ---- gram: wave w -> m-tile (w&7), g-half (w>>3) ----
    {
        uint32_t* D32 = (uint32_t*)Pb[0];           // row stride 68 u32 (permuted cols)
        float* G = ws + OFS_G;
        int mt = w & 7, gh = w >> 3;
        short8_t af[5];
        #pragma unroll
        for (int s = 0; s < 5; ++s)
            af[s] = *(const short8_t*)&ABf[(mt * 16 + col) * 168 + s * 32 + quad * 8];
        #pragma unroll
        for (int gi = 0; gi < 2; ++gi) {
            int g = gh * 2 + gi;
            short8_t b0[5], b1[5];
            #pragma unroll
            for (int s = 0; s < 5; ++s) {
                b0[s] = *(const short8_t*)&ABf[((2 * g) * 16 + col) * 168 + s * 32 + quad * 8];
                b1[s] = *(const short8_t*)&ABf[((2 * g + 1) * 16 + col) * 168 + s * 32 + quad * 8];
            }
            f32x4 a0 = (f32x4){0.f, 0.f, 0.f, 0.f};
            f32x4 a1 = (f32x4){0.f, 0.f, 0.f, 0.f};
            #pragma unroll
            for (int s = 0; s < 5; ++s) {
                a0 = __builtin_amdgcn_mfma_f32_16x16x32_bf16(af[s], b0[s], a0, 0, 0, 0);
                a1 = __builtin_amdgcn_mfma_f32_16x16x32_bf16(af[s], b1[s], a1, 0, 0, 0);
            }
            #pragma unroll
            for (int r = 0; r < 4; ++r) {
                int m = mt * 16 + quad * 4 + r;
                G[m * 128 + g * 32 + col] = a0[r];
                G[m * 128 + g * 32 + 16 + col] = a1[r];
                D32[m * 68 + g * 16 + col] = pack_bf(a0[r], a1[r]);
            }
        }
    }
    __syncthreads();

    // ---- power: 8 squarings; wave w -> m-tile (w&7), n-quarter (w>>3) ----
    int cur = 0;
    #pragma unroll 1
    for (int j = 0; j < 8; ++j) {
        float trn = tr_arr[j];
        float inv2 = 1.0f / (trn * trn);
        const unsigned short* S = Pb[cur];
        uint32_t* D32 = (uint32_t*)Pb[cur ^ 1];     // row stride 68 u32
        int mt = w & 7, nh = w >> 3;
        short8_t af[4];
        #pragma unroll
        for (int s = 0; s < 4; ++s)
            af[s] = *(const short8_t*)&S[(mt * 16 + col) * PSTR + s * 32 + quad * 8];
        #pragma unroll
        for (int pr = 0; pr < 2; ++pr) {
            int ntE = 4 * nh + 2 * pr, ntO = ntE + 1;
            short8_t bE[4], bO[4];
            #pragma unroll
            for (int s = 0; s < 4; ++s) {
                bE[s] = *(const short8_t*)&S[(ntE * 16 + col) * PSTR + s * 32 + quad * 8];
                bO[s] = *(const short8_t*)&S[(ntO * 16 + col) * PSTR + s * 32 + quad * 8];
            }
            f32x4 aE = (f32x4){0.f, 0.f, 0.f, 0.f};
            f32x4 aO = (f32x4){0.f, 0.f, 0.f, 0.f};
            #pragma unroll
            for (int s = 0; s < 4; ++s) {
                aE = __builtin_amdgcn_mfma_f32_16x16x32_bf16(af[s], bE[s], aE, 0, 0, 0);
                aO = __builtin_amdgcn_mfma_f32_16x16x32_bf16(af[s], bO[s], aO, 0, 0, 0);
            }
            int nE = ntE * 16 + col, nO = ntO * 16 + col;
            #pragma unroll
            for (int r = 0; r < 4; ++r) {
                float x0 = aE[r] * inv2, x1 = aO[r] * inv2;
                int row = mt * 16 + quad * 4 + r;
                D32[row * 68 + (ntE >> 1) * 16 + col] = pack_bf(x0, x1);
                if (row == nE) atomicAdd(&tr_arr[j + 1], x0);
                if (row == nO) atomicAdd(&tr_arr[j + 1], x1);
            }
        }
        __syncthreads();
        cur ^= 1;
    }

    // ---- Rayleigh on f32 G (8 threads/row) ----
    {
        int a = t >> 3, sub = t & 7;
        const unsigned short* S = Pb[cur];
        float s = 0.f;
        #pragma unroll
        for (int k = 0; k < 16; ++k) s += bf2f(S[a * PSTR + sub * 16 + k]);
        s += __shfl_xor(s, 1, 8); s += __shfl_xor(s, 2, 8); s += __shfl_xor(s, 4, 8);
        if (sub == 0) v[a] = s;
    }
    __syncthreads();
    {
        int a = t >> 3, sub = t & 7;
        const float* G = ws + OFS_G;
        float wv = 0.f;
        #pragma unroll
        for (int k = 0; k < 16; ++k)
            wv = fmaf(G[a * 128 + sub * 16 + k], v[sub * 16 + k], wv);
        wv += __shfl_xor(wv, 1, 8); wv += __shfl_xor(wv, 2, 8); wv += __shfl_xor(wv, 4, 8);
        if (sub == 0) { red[a] = v[a] * wv; red[128 + a] = v[a] * v[a]; }
    }
    __syncthreads();
    for (int off = 64; off > 0; off >>= 1) {
        if (t < off) { red[t] += red[t + off]; red[128 + t] += red[128 + t + off]; }
        __syncthreads();
    }
    if (t == 0) {
        float lam = red[0] / red[128];               // sigma^2 = lammax(G)
        float mu = fmaxf(mu_p[0], 0.0f);
        ws[OFS_SC + 16] = 1.0f / (lam * mu);                  // X scale
        ws[OFS_SC + 17] = 1.0f / (sqrtf(lam) * sqrtf(mu));    // atom scale
    }
}

// ---- finalize: XPB (bf16, k-permuted) ; ATB ; ANTBP (n-permuted) ; goal ; pm ----
__global__ __launch_bounds__(256) void k_finalize(float* ws, const float* y) {
    int idx = blockIdx.x * 256 + threadIdx.x;       // grid 392 -> 100352
    float scX = ws[OFS_SC + 16], scA = ws[OFS_SC + 17];
    if (idx < 16384) {
        int n = idx >> 7, ks = idx & 127;
        int g = ks >> 5, rem = ks & 31, u = rem >> 1, v = rem & 1;
        int k = g * 32 + v * 16 + u;                // pi^-1(ks)
        ((unsigned short*)(ws + OFS_X))[idx] = f2bf(ws[OFS_G + n * 128 + k] * scX);
    } else if (idx < 36864) {
        int e = idx - 16384;                        // ATB [n=128][k=160] zero-pad
        int n = e / 160, k = e - n * 160;
        float v = (k < 144) ? ws[OFS_AF1 + n * 144 + k] * scA : 0.f;
        ((unsigned short*)(ws + OFS_ATB))[e] = f2bf(v);
    } else if (idx < 55296) {
        int e = idx - 36864;                        // ANTBP [jpix=144][ks=128]
        int jp = e >> 7, ks = e & 127;
        int g = ks >> 5, rem = ks & 31, u = rem >> 1, v = rem & 1;
        int n = g * 32 + v * 16 + u;                // pi^-1(ks)
        ((unsigned short*)(ws + OFS_ANTB))[e] = f2bf(ws[OFS_AF1 + n * 144 + jp] * scA);
    } else {
        int e = idx - 55296;                        // < 45056
        if (e < 45000) ws[OFS_GOAL + e] = y[e];
        if (e < 32768) {
            int b = e >> 12, pi = (e >> 6) & 63, pj = e & 63;
            const float* yb = y + b * 5625;
            float s = 0.f;
            for (int di = 0; di < 12; ++di) {
                const float* row = yb + (pi + di) * 75 + pj;
                #pragma unroll
                for (int dj = 0; dj < 12; ++dj) s += row[dj];
            }
            ws[OFS_PM + e] = s * (1.0f / 144.0f);
        }
    }
}

// ---- fused megakernel: q (im2col MFMA) + FISTA(15)+1 + pred.
//      Epilogue state as f32x2 pairs (nt0,nt1) -> v_pk_*_f32 packed VALU. ----
__global__ __launch_bounds__(256) void k_fista(const unsigned short* XPB, const float* goal,
                                               const unsigned short* ATB,
                                               const unsigned short* ANTBP,
                                               const float* pm, float* cfg, float* pred,
                                               const float* mu_p, int first, int write_cf) {
    __shared__ float gls[12 * 44];
    __shared__ unsigned short Atile[32 * 168];
    __shared__ unsigned short Zbuf[2][32 * 136];
    int t = threadIdx.x;
    int lane = t & 63, w = t >> 6;
    int col = lane & 15, quad = lane >> 4;
    int nb = w * 32;
    int blk = blockIdx.x;
    int b = blk >> 7, pi = (blk >> 1) & 63, h = blk & 1;
    int p0 = blk * 32;
    float mu = fmaxf(mu_p[0], 0.0f);
    const f32x2 mu2 = (f32x2){mu, mu};
    const f32x2 lam2 = (f32x2){LAM, LAM};
    const f32x2 nlam2 = (f32x2){-LAM, -LAM};

    // ---- stage goal slice (12 x 44, zero-pad past col 74) ----
    for (int e = t; e < 528; e += 256) {
        int r = e / 44, cc = e - r * 44;
        int gc = h * 32 + cc;
        gls[e] = (gc < 75) ? goal[b * 5625 + (pi + r) * 75 + gc] : 0.f;
    }
    __syncthreads();
    // ---- im2col A-tile 32 x 160 bf16, pair-packed b32 writes ----
    {
        uint32_t* A32 = (uint32_t*)Atile;          // row stride 84 u32
        #pragma unroll
        for (int i = 0; i < 10; ++i) {
            int pe = t + i * 256;                  // < 2560 = 32m * 80 pairs
            int m = pe / 80, q32 = pe - m * 80;
            int kk = q32 * 2;
            float v0 = 0.f, v1 = 0.f;
            if (kk < 144) {
                int di = kk / 12, dj = kk - di * 12;
                v0 = gls[di * 44 + m + dj];
                int k1 = kk + 1, di1 = k1 / 12, dj1 = k1 - di1 * 12;
                v1 = gls[di1 * 44 + m + dj1];
            }
            A32[m * 84 + q32] = pack_bf(v0, v1);
        }
    }
    __syncthreads();

    // ---- q-matmul: qv2[mt][r] = {q(nt0), q(nt1)} in C/D layout ----
    f32x2 qv2[2][4];
    {
        short8_t bfq[2][5];
        #pragma unroll
        for (int nt = 0; nt < 2; ++nt)
            #pragma unroll
            for (int s = 0; s < 5; ++s)
                bfq[nt][s] = *(const short8_t*)&ATB[(nb + nt * 16 + col) * 160 + s * 32 + quad * 8];
        #pragma unroll
        for (int mt = 0; mt < 2; ++mt) {
            short8_t af[5];
            #pragma unroll
            for (int s = 0; s < 5; ++s)
                af[s] = *(const short8_t*)&Atile[(mt * 16 + col) * 168 + s * 32 + quad * 8];
            f32x4 acc0 = (f32x4){0.f, 0.f, 0.f, 0.f};
            f32x4 acc1 = (f32x4){0.f, 0.f, 0.f, 0.f};
            #pragma unroll
            for (int s = 0; s < 5; ++s) {
                acc0 = __builtin_amdgcn_mfma_f32_16x16x32_bf16(af[s], bfq[0][s], acc0, 0, 0, 0);
                acc1 = __builtin_amdgcn_mfma_f32_16x16x32_bf16(af[s], bfq[1][s], acc1, 0, 0, 0);
            }
            #pragma unroll
            for (int r = 0; r < 4; ++r) qv2[mt][r] = (f32x2){acc0[r], acc1[r]};
        }
    }

    // ---- X B-fragments: contiguous b128 from pre-permuted bf16 XPB ----
    short8_t xf[2][4];
    #pragma unroll
    for (int nt = 0; nt < 2; ++nt)
        #pragma unroll
        for (int s = 0; s < 4; ++s)
            xf[nt][s] = *(const short8_t*)&XPB[(nb + nt * 16 + col) * 128 + s * 32 + quad * 8];

    // ---- c0 / z0 init, seed Z (paired b32, interleaved cols) ----
    uint32_t* Z32w = (uint32_t*)Zbuf[0];           // row stride 68 u32
    f32x2 cv2[2][4], zo2[2][4];
    #pragma unroll
    for (int mt = 0; mt < 2; ++mt)
        #pragma unroll
        for (int r = 0; r < 4; ++r) {
            int row = mt * 16 + quad * 4 + r;
            int p = p0 + row;
            float c0 = 0.f, c1 = 0.f;
            if (!first) {
                c0 = cfg[p * 128 + nb + col];
                c1 = cfg[p * 128 + nb + 16 + col];
            }
            cv2[mt][r] = (f32x2){c0, c1};
            zo2[mt][r] = (f32x2){c0, c1};
            Z32w[row * 68 + 16 * w + col] = pack_bf(c0, c1);
        }
    __syncthreads();

    f32x4 acc[2][2];
    auto matmul = [&](const unsigned short* Zr) {
        short8_t af[2][4];
        #pragma unroll
        for (int mt = 0; mt < 2; ++mt)
            #pragma unroll
            for (int s = 0; s < 4; ++s)
                af[mt][s] = *(const short8_t*)&Zr[(mt * 16 + col) * 136 + s * 32 + quad * 8];
        #pragma unroll
        for (int mt = 0; mt < 2; ++mt)
            #pragma unroll
            for (int nt = 0; nt < 2; ++nt)
                acc[mt][nt] = (f32x4){0.f, 0.f, 0.f, 0.f};
        #pragma unroll
        for (int s = 0; s < 4; ++s)
            #pragma unroll
            for (int mt = 0; mt < 2; ++mt)
                #pragma unroll
                for (int nt = 0; nt < 2; ++nt)
                    acc[mt][nt] = __builtin_amdgcn_mfma_f32_16x16x32_bf16(
                        af[mt][s], xf[nt][s], acc[mt][nt], 0, 0, 0);
    };

    float tm = 1.0f;
    int cur = 0;
    #pragma unroll 1
    for (int it = 0; it < 14; ++it) {          // FISTA iters 1..14 (write z)
        matmul(Zbuf[cur]);
        float tnn = 0.5f * (1.0f + sqrtf(1.0f + 4.0f * tm * tm));
        float fm = (tm - 1.0f) / tnn;
        tm = tnn;
        f32x2 fm2 = (f32x2){fm, fm};
        uint32_t* Zw = (uint32_t*)Zbuf[cur ^ 1];
        #pragma unroll
        for (int mt = 0; mt < 2; ++mt)
            #pragma unroll
            for (int r = 0; r < 4; ++r) {
                f32x2 a2 = (f32x2){acc[mt][0][r], acc[mt][1][r]};
                f32x2 u2 = mu2 * (qv2[mt][r] - a2) + zo2[mt][r];
                f32x2 cl2 = __builtin_elementwise_min(
                                __builtin_elementwise_max(u2, nlam2), lam2);
                f32x2 cn2 = u2 - cl2;
                f32x2 zn2 = fm2 * (cn2 - cv2[mt][r]) + cn2;
                cv2[mt][r] = cn2;
                zo2[mt][r] = zn2;
                Zw[(mt * 16 + quad * 4 + r) * 68 + 16 * w + col] = pack_bf(zn2[0], zn2[1]);
            }
        __syncthreads();
        cur ^= 1;
    }
    {   // FISTA iter 15: compute c15; stage c15 (z15 never consumed)
        matmul(Zbuf[cur]);
        uint32_t* Zw = (uint32_t*)Zbuf[cur ^ 1];
        #pragma unroll
        for (int mt = 0; mt < 2; ++mt)
            #pragma unroll
            for (int r = 0; r < 4; ++r) {
                f32x2 a2 = (f32x2){acc[mt][0][r], acc[mt][1][r]};
                f32x2 u2 = mu2 * (qv2[mt][r] - a2) + zo2[mt][r];
                f32x2 cl2 = __builtin_elementwise_min(
                                __builtin_elementwise_max(u2, nlam2), lam2);
                f32x2 cn2 = u2 - cl2;
                cv2[mt][r] = cn2;
                Zw[(mt * 16 + quad * 4 + r) * 68 + 16 * w + col] = pack_bf(cn2[0], cn2[1]);
            }
        __syncthreads();
        cur ^= 1;
    }
    {   // final differentiable step: cf = prox(c15 + mu*(q - X@c15)); stage cf
        matmul(Zbuf[cur]);
        uint32_t* Zw = (uint32_t*)Zbuf[cur ^ 1];
        #pragma unroll
        for (int mt = 0; mt < 2; ++mt)
            #pragma unroll
            for (int r = 0; r < 4; ++r) {
                int row = mt * 16 + quad * 4 + r;
                f32x2 a2 = (f32x2){acc[mt][0][r], acc[mt][1][r]};
                f32x2 u2 = mu2 * (qv2[mt][r] - a2) + cv2[mt][r];
                f32x2 cl2 = __builtin_elementwise_min(
                                __builtin_elementwise_max(u2, nlam2), lam2);
                f32x2 cf2 = u2 - cl2;
                if (write_cf) {
                    cfg[(p0 + row) * 128 + nb + col] = cf2[0];
                    cfg[(p0 + row) * 128 + nb + 16 + col] = cf2[1];
                }
                Zw[row * 68 + 16 * w + col] = pack_bf(cf2[0], cf2[1]);
            }
        __syncthreads();
        cur ^= 1;
    }

    // ---- pred tail: pred[32][144] = cf @ atoms_n + pm (B pre-permuted ANTBP) ----
    {
        int jt0 = (w == 0) ? 0 : (2 * w + 1);
        int jtn = (w == 0) ? 3 : 2;
        const unsigned short* Zr = Zbuf[cur];
        short8_t af[2][4];
        #pragma unroll
        for (int mt = 0; mt < 2; ++mt)
            #pragma unroll
            for (int s = 0; s < 4; ++s)
                af[mt][s] = *(const short8_t*)&Zr[(mt * 16 + col) * 136 + s * 32 + quad * 8];
        f32x4 accp[2][3];
        #pragma unroll
        for (int mt = 0; mt < 2; ++mt)
            #pragma unroll
            for (int ji = 0; ji < 3; ++ji)
                accp[mt][ji] = (f32x4){0.f, 0.f, 0.f, 0.f};
        #pragma unroll
        for (int ji = 0; ji < 3; ++ji) {
            if (ji < jtn) {
                int jt = jt0 + ji;
                short8_t bf4[4];
                #pragma unroll
                for (int s = 0; s < 4; ++s)
                    bf4[s] = *(const short8_t*)&ANTBP[(jt * 16 + col) * 128 + s * 32 + quad * 8];
                #pragma unroll
                for (int mt = 0; mt < 2; ++mt)
                    #pragma unroll
                    for (int s = 0; s < 4; ++s)
                        accp[mt][ji] = __builtin_amdgcn_mfma_f32_16x16x32_bf16(
                            af[mt][s], bf4[s], accp[mt][ji], 0, 0, 0);
            }
        }
        #pragma unroll
        for (int mt = 0; mt < 2; ++mt)
            #pragma unroll
            for (int r = 0; r < 4; ++r) {
                int p = p0 + mt * 16 + quad * 4 + r;
                float pmv = pm[p];
                #pragma unroll
                for (int ji = 0; ji < 3; ++ji)
                    if (ji < jtn)
                        pred[p * 144 + (jt0 + ji) * 16 + col] = accp[mt][ji][r] + pmv;
            }
    }
}

// ---- fold via LDS staging: block = (output row i, batch b); coalesced pred reads. ----
__global__ __launch_bounds__(256) void k_fold(const float* y, const float* beta_p,
                                              const float* pred, float* goal,
                                              float* out, int write_out) {
    __shared__ float P[12 * 832];              // 39,936 B
    int i = blockIdx.x, b = blockIdx.y;
    int t = threadIdx.x;
    for (int di = 0; di < 12; ++di) {
        int pi = i - di;
        if ((unsigned)pi >= 64u) continue;     // uniform per block
        int base = (b << 12) + (pi << 6);
        #pragma unroll
        for (int it = 0; it < 3; ++it) {
            int e = t + it * 256;              // < 768 = 64 pj * 12 dj
            int pj = e / 12, dj = e - pj * 12;
            P[di * 832 + pj * 13 + dj] = pred[(base + pj) * AA + di * 12 + dj];
        }
    }
    __syncthreads();
    if (t >= 75) return;
    int j = t;
    float S = 0.f;
    for (int di = 0; di < 12; ++di) {
        if ((unsigned)(i - di) >= 64u) continue;
        const float* Pd = &P[di * 832];
        #pragma unroll
        for (int dj = 0; dj < 12; ++dj) {
            int pj = j - dj;
            if ((unsigned)pj >= 64u) continue;
            S += Pd[pj * 13 + dj];
        }
    }
    int ci = min(i, 11) - max(i - 63, 0) + 1;
    int cj = min(j, 11) - max(j - 63, 0) + 1;
    float beta = fmaxf(beta_p[0], 0.0f);
    int idx = i * 75 + j;
    float yv = y[b * 5625 + idx];
    float g = (yv + beta * S) / (1.0f + beta * (float)(ci * cj));
    if (write_out) out[b * 5625 + idx] = g;
    else           goal[b * 5625 + idx] = g;
}

extern "C" void kernel_launch(void* const* d_in, const int* in_sizes, int n_in,
                              void* d_out, int out_size, void* d_ws, size_t ws_size,
                              hipStream_t stream) {
    const float* y     = (const float*)d_in[0];
    const float* atoms = (const float*)d_in[1];
    const float* beta  = (const float*)d_in[2];
    const float* mu    = (const float*)d_in[3];
    float* out = (float*)d_out;
    float* ws = (float*)d_ws;

    k_setup<<<1, 1024, 0, stream>>>(atoms, mu, ws); // norm + gram + power + Rayleigh
    k_finalize<<<392, 256, 0, stream>>>(ws, y);     // XPB + ATB + ANTBP + goal + pm

    for (int u = 0; u < 2; ++u) {
        k_fista<<<1024, 256, 0, stream>>>((const unsigned short*)(ws + OFS_X),
                                          ws + OFS_GOAL,
                                          (const unsigned short*)(ws + OFS_ATB),
                                          (const unsigned short*)(ws + OFS_ANTB),
                                          ws + OFS_PM, ws + OFS_CF, ws + OFS_PRED,
                                          mu, u == 0 ? 1 : 0, u == 0 ? 1 : 0);
        k_fold<<<dim3(75, 8), 256, 0, stream>>>(y, beta, ws + OFS_PRED,
                                                ws + OFS_GOAL, out, u == 1 ? 1 : 0);
    }
}

// Round 17
// 214.083 us; speedup vs baseline: 1.3403x; 1.0076x over previous
//
#include <hip/hip_runtime.h>
#include <stdint.h>

// Problem constants
#define AA 144          // ATOM*ATOM
#define LAM 0.1f

// ---- workspace layout (float offsets) ----
#define OFS_SC    0            // 64 scalars: [16]=scX, [17]=scA
#define OFS_AF1   64           // 128*144 row-normalized zero-mean atoms
#define OFS_G     36928        // 128*128 gram (f32)
#define OFS_S0    53312        // ATB (bf16 atoms, [128][160] u16)
#define OFS_S1    69696        // ANTBP (bf16 atomsT, n-permuted, [144][128] u16)
#define OFS_X     86080        // XPB: bf16 X, k-permuted, [128][128] u16
#define OFS_PM    139328       // 32768 patch means
#define OFS_GOAL  172096       // 45056 goal (f32)
#define OFS_CF    4411456      // 32768*128
#define OFS_PRED  8605760      // 32768*144
#define OFS_ATB   OFS_S0
#define OFS_ANTB  OFS_S1

// Contraction-dim permutation: real n = 32g + 16v + u  <->  stored ks = 32g + 2u + v.
// A and B sides both use stored order -> dot products unchanged.

typedef __attribute__((ext_vector_type(8))) short short8_t;
typedef __attribute__((ext_vector_type(4))) float f32x4;
typedef __attribute__((ext_vector_type(2))) float f32x2;

__device__ __forceinline__ unsigned short f2bf(float f) {      // RNE
    union { float f; uint32_t u; } x; x.f = f;
    uint32_t u = x.u;
    return (unsigned short)((u + 0x7FFFu + ((u >> 16) & 1u)) >> 16);
}
__device__ __forceinline__ float bf2f(unsigned short u) {
    union { float f; uint32_t i; } x; x.i = ((uint32_t)u) << 16; return x.f;
}
// pack two f32 -> packed bf16 pair (a->low, b->high), round-half-up
__device__ __forceinline__ uint32_t pack_bf(float a, float b) {
    union { float f; uint32_t u; } xa, xb; xa.f = a; xb.f = b;
    return __builtin_amdgcn_perm(xb.u + 0x8000u, xa.u + 0x8000u, 0x07060302u);
}

// ---- setup: block 0 = norm + bf16 gram + 8x power squarings + Rayleigh (1024 thr);
//      blocks 1..45 = goal copy + patch means (run hidden under block 0's chain). ----
#define PSTR 136
__global__ __launch_bounds__(1024) void k_setup(const float* atoms, const float* mu_p,
                                                float* ws, const float* y) {
    __shared__ unsigned short ABf[128 * 168];       // 43008 B
    __shared__ unsigned short Pb[2][128 * PSTR];    // 69632 B
    __shared__ float tr_arr[10];
    __shared__ float v[128];
    __shared__ float red[256];
    int t = threadIdx.x;
    if (blockIdx.x != 0) {                          // worker blocks: goal + pm
        int e = (blockIdx.x - 1) * 1024 + t;        // < 46080
        if (e < 45000) ws[OFS_GOAL + e] = y[e];
        if (e < 32768) {
            int b = e >> 12, pi = (e >> 6) & 63, pj = e & 63;
            const float* yb = y + b * 5625;
            float s = 0.f;
            for (int di = 0; di < 12; ++di) {
                const float* row = yb + (pi + di) * 75 + pj;
                #pragma unroll
                for (int dj = 0; dj < 12; ++dj) s += row[dj];
            }
            ws[OFS_PM + e] = s * (1.0f / 144.0f);
        }
        return;
    }
    int lane = t & 63, w = t >> 6;
    int col = lane & 15, quad = lane >> 4;
    if (t < 10) tr_arr[t] = (t == 0) ? 128.0f : 0.f;

    // ---- norm: 8 threads/atom, width-8 shfl reductions ----
    {
        int a = t >> 3, sub = t & 7;
        const float* ap = atoms + a * AA + sub * 18;
        float s = 0.f;
        #pragma unroll
        for (int k = 0; k < 18; ++k) s += ap[k];
        s += __shfl_xor(s, 1, 8); s += __shfl_xor(s, 2, 8); s += __shfl_xor(s, 4, 8);
        float mean = s * (1.0f / 144.0f);
        float ss = 0.f;
        #pragma unroll
        for (int k = 0; k < 18; ++k) { float d = ap[k] - mean; ss = fmaf(d, d, ss); }
        ss += __shfl_xor(ss, 1, 8); ss += __shfl_xor(ss, 2, 8); ss += __shfl_xor(ss, 4, 8);
        float rn = 1.0f / sqrtf(ss);
        #pragma unroll
        for (int k = 0; k < 18; ++k) {
            float av = (ap[k] - mean) * rn;
            ws[OFS_AF1 + a * AA + sub * 18 + k] = av;
            ABf[a * 168 + sub * 18 + k] = f2bf(av);
        }
        if (sub == 0) {
            #pragma unroll
            for (int k = AA; k < 160; ++k) ABf[a * 168 + k] = 0;
        }
    }
    __syncthreads();

    // ---- gram: wave w -> m-tile (w&7), g-half (w>>3) ----
    {
        uint32_t* D32 = (uint32_t*)Pb[0];
        float* G = ws + OFS_G;
        int mt = w & 7, gh = w >> 3;
        short8_t af[5];
        #pragma unroll
        for (int s = 0; s < 5; ++s)
            af[s] = *(const short8_t*)&ABf[(mt * 16 + col) * 168 + s * 32 + quad * 8];
        #pragma unroll
        for (int gi = 0; gi < 2; ++gi) {
            int g = gh * 2 + gi;
            short8_t b0[5], b1[5];
            #pragma unroll
            for (int s = 0; s < 5; ++s) {
                b0[s] = *(const short8_t*)&ABf[((2 * g) * 16 + col) * 168 + s * 32 + quad * 8];
                b1[s] = *(const short8_t*)&ABf[((2 * g + 1) * 16 + col) * 168 + s * 32 + quad * 8];
            }
            f32x4 a0 = (f32x4){0.f, 0.f, 0.f, 0.f};
            f32x4 a1 = (f32x4){0.f, 0.f, 0.f, 0.f};
            #pragma unroll
            for (int s = 0; s < 5; ++s) {
                a0 = __builtin_amdgcn_mfma_f32_16x16x32_bf16(af[s], b0[s], a0, 0, 0, 0);
                a1 = __builtin_amdgcn_mfma_f32_16x16x32_bf16(af[s], b1[s], a1, 0, 0, 0);
            }
            #pragma unroll
            for (int r = 0; r < 4; ++r) {
                int m = mt * 16 + quad * 4 + r;
                G[m * 128 + g * 32 + col] = a0[r];
                G[m * 128 + g * 32 + 16 + col] = a1[r];
                D32[m * 68 + g * 16 + col] = pack_bf(a0[r], a1[r]);
            }
        }
    }
    __syncthreads();

    // ---- power: 8 squarings; wave w -> m-tile (w&7), n-quarter (w>>3) ----
    int cur = 0;
    #pragma unroll 1
    for (int j = 0; j < 8; ++j) {
        float trn = tr_arr[j];
        float inv2 = 1.0f / (trn * trn);
        const unsigned short* S = Pb[cur];
        uint32_t* D32 = (uint32_t*)Pb[cur ^ 1];
        int mt = w & 7, nh = w >> 3;
        short8_t af[4];
        #pragma unroll
        for (int s = 0; s < 4; ++s)
            af[s] = *(const short8_t*)&S[(mt * 16 + col) * PSTR + s * 32 + quad * 8];
        #pragma unroll
        for (int pr = 0; pr < 2; ++pr) {
            int ntE = 4 * nh + 2 * pr, ntO = ntE + 1;
            short8_t bE[4], bO[4];
            #pragma unroll
            for (int s = 0; s < 4; ++s) {
                bE[s] = *(const short8_t*)&S[(ntE * 16 + col) * PSTR + s * 32 + quad * 8];
                bO[s] = *(const short8_t*)&S[(ntO * 16 + col) * PSTR + s * 32 + quad * 8];
            }
            f32x4 aE = (f32x4){0.f, 0.f, 0.f, 0.f};
            f32x4 aO = (f32x4){0.f, 0.f, 0.f, 0.f};
            #pragma unroll
            for (int s = 0; s < 4; ++s) {
                aE = __builtin_amdgcn_mfma_f32_16x16x32_bf16(af[s], bE[s], aE, 0, 0, 0);
                aO = __builtin_amdgcn_mfma_f32_16x16x32_bf16(af[s], bO[s], aO, 0, 0, 0);
            }
            int nE = ntE * 16 + col, nO = ntO * 16 + col;
            #pragma unroll
            for (int r = 0; r < 4; ++r) {
                float x0 = aE[r] * inv2, x1 = aO[r] * inv2;
                int row = mt * 16 + quad * 4 + r;
                D32[row * 68 + (ntE >> 1) * 16 + col] = pack_bf(x0, x1);
                if (row == nE) atomicAdd(&tr_arr[j + 1], x0);
                if (row == nO) atomicAdd(&tr_arr[j + 1], x1);
            }
        }
        __syncthreads();
        cur ^= 1;
    }

    // ---- Rayleigh on f32 G (8 threads/row) ----
    {
        int a = t >> 3, sub = t & 7;
        const unsigned short* S = Pb[cur];
        float s = 0.f;
        #pragma unroll
        for (int k = 0; k < 16; ++k) s += bf2f(S[a * PSTR + sub * 16 + k]);
        s += __shfl_xor(s, 1, 8); s += __shfl_xor(s, 2, 8); s += __shfl_xor(s, 4, 8);
        if (sub == 0) v[a] = s;
    }
    __syncthreads();
    {
        int a = t >> 3, sub = t & 7;
        const float* G = ws + OFS_G;
        float wv = 0.f;
        #pragma unroll
        for (int k = 0; k < 16; ++k)
            wv = fmaf(G[a * 128 + sub * 16 + k], v[sub * 16 + k], wv);
        wv += __shfl_xor(wv, 1, 8); wv += __shfl_xor(wv, 2, 8); wv += __shfl_xor(wv, 4, 8);
        if (sub == 0) { red[a] = v[a] * wv; red[128 + a] = v[a] * v[a]; }
    }
    __syncthreads();
    for (int off = 64; off > 0; off >>= 1) {
        if (t < off) { red[t] += red[t + off]; red[128 + t] += red[128 + t + off]; }
        __syncthreads();
    }
    if (t == 0) {
        float lam = red[0] / red[128];
        float mu = fmaxf(mu_p[0], 0.0f);
        ws[OFS_SC + 16] = 1.0f / (lam * mu);
        ws[OFS_SC + 17] = 1.0f / (sqrtf(lam) * sqrtf(mu));
    }
}

// ---- finalize: only the scale-dependent tables (XPB / ATB / ANTBP) ----
__global__ __launch_bounds__(256) void k_finalize(float* ws) {
    int idx = blockIdx.x * 256 + threadIdx.x;       // grid 216 -> 55296
    float scX = ws[OFS_SC + 16], scA = ws[OFS_SC + 17];
    if (idx < 16384) {
        int n = idx >> 7, ks = idx & 127;
        int g = ks >> 5, rem = ks & 31, u = rem >> 1, v = rem & 1;
        int k = g * 32 + v * 16 + u;
        ((unsigned short*)(ws + OFS_X))[idx] = f2bf(ws[OFS_G + n * 128 + k] * scX);
    } else if (idx < 36864) {
        int e = idx - 16384;                        // ATB [n=128][k=160] zero-pad
        int n = e / 160, k = e - n * 160;
        float v = (k < 144) ? ws[OFS_AF1 + n * 144 + k] * scA : 0.f;
        ((unsigned short*)(ws + OFS_ATB))[e] = f2bf(v);
    } else {
        int e = idx - 36864;                        // ANTBP [j=144][ks=128]
        int jp = e >> 7, ks = e & 127;
        int g = ks >> 5, rem = ks & 31, u = rem >> 1, v = rem & 1;
        int n = g * 32 + v * 16 + u;
        ((unsigned short*)(ws + OFS_ANTB))[e] = f2bf(ws[OFS_AF1 + n * 144 + jp] * scA);
    }
}

// ---- fused megakernel: q (im2col MFMA) + FISTA(15)+1 + pred.
//      Epilogue state as f32x2 pairs (nt0,nt1) -> v_pk_*_f32 packed VALU. (R15 champion) ----
__global__ __launch_bounds__(256) void k_fista(const unsigned short* XPB, const float* goal,
                                               const unsigned short* ATB,
                                               const unsigned short* ANTBP,
                                               const float* pm, float* cfg, float* pred,
                                               const float* mu_p, int first, int write_cf) {
    __shared__ float gls[12 * 44];
    __shared__ unsigned short Atile[32 * 168];
    __shared__ unsigned short Zbuf[2][32 * 136];
    int t = threadIdx.x;
    int lane = t & 63, w = t >> 6;
    int col = lane & 15, quad = lane >> 4;
    int nb = w * 32;
    int blk = blockIdx.x;
    int b = blk >> 7, pi = (blk >> 1) & 63, h = blk & 1;
    int p0 = blk * 32;
    float mu = fmaxf(mu_p[0], 0.0f);
    const f32x2 mu2 = (f32x2){mu, mu};
    const f32x2 lam2 = (f32x2){LAM, LAM};
    const f32x2 nlam2 = (f32x2){-LAM, -LAM};

    // ---- stage goal slice (12 x 44, zero-pad past col 74) ----
    for (int e = t; e < 528; e += 256) {
        int r = e / 44, cc = e - r * 44;
        int gc = h * 32 + cc;
        gls[e] = (gc < 75) ? goal[b * 5625 + (pi + r) * 75 + gc] : 0.f;
    }
    __syncthreads();
    // ---- im2col A-tile 32 x 160 bf16, pair-packed b32 writes ----
    {
        uint32_t* A32 = (uint32_t*)Atile;          // row stride 84 u32
        #pragma unroll
        for (int i = 0; i < 10; ++i) {
            int pe = t + i * 256;                  // < 2560 = 32m * 80 pairs
            int m = pe / 80, q32 = pe - m * 80;
            int kk = q32 * 2;
            float v0 = 0.f, v1 = 0.f;
            if (kk < 144) {
                int di = kk / 12, dj = kk - di * 12;
                v0 = gls[di * 44 + m + dj];
                int k1 = kk + 1, di1 = k1 / 12, dj1 = k1 - di1 * 12;
                v1 = gls[di1 * 44 + m + dj1];
            }
            A32[m * 84 + q32] = pack_bf(v0, v1);
        }
    }
    __syncthreads();

    // ---- q-matmul: qv2[mt][r] = {q(nt0), q(nt1)} in C/D layout ----
    f32x2 qv2[2][4];
    {
        short8_t bfq[2][5];
        #pragma unroll
        for (int nt = 0; nt < 2; ++nt)
            #pragma unroll
            for (int s = 0; s < 5; ++s)
                bfq[nt][s] = *(const short8_t*)&ATB[(nb + nt * 16 + col) * 160 + s * 32 + quad * 8];
        #pragma unroll
        for (int mt = 0; mt < 2; ++mt) {
            short8_t af[5];
            #pragma unroll
            for (int s = 0; s < 5; ++s)
                af[s] = *(const short8_t*)&Atile[(mt * 16 + col) * 168 + s * 32 + quad * 8];
            f32x4 acc0 = (f32x4){0.f, 0.f, 0.f, 0.f};
            f32x4 acc1 = (f32x4){0.f, 0.f, 0.f, 0.f};
            #pragma unroll
            for (int s = 0; s < 5; ++s) {
                acc0 = __builtin_amdgcn_mfma_f32_16x16x32_bf16(af[s], bfq[0][s], acc0, 0, 0, 0);
                acc1 = __builtin_amdgcn_mfma_f32_16x16x32_bf16(af[s], bfq[1][s], acc1, 0, 0, 0);
            }
            #pragma unroll
            for (int r = 0; r < 4; ++r) qv2[mt][r] = (f32x2){acc0[r], acc1[r]};
        }
    }

    // ---- X B-fragments: contiguous b128 from pre-permuted bf16 XPB ----
    short8_t xf[2][4];
    #pragma unroll
    for (int nt = 0; nt < 2; ++nt)
        #pragma unroll
        for (int s = 0; s < 4; ++s)
            xf[nt][s] = *(const short8_t*)&XPB[(nb + nt * 16 + col) * 128 + s * 32 + quad * 8];

    // ---- c0 / z0 init, seed Z (paired b32, interleaved cols) ----
    uint32_t* Z32w = (uint32_t*)Zbuf[0];           // row stride 68 u32
    f32x2 cv2[2][4], zo2[2][4];
    #pragma unroll
    for (int mt = 0; mt < 2; ++mt)
        #pragma unroll
        for (int r = 0; r < 4; ++r) {
            int row = mt * 16 + quad * 4 + r;
            int p = p0 + row;
            float c0 = 0.f, c1 = 0.f;
            if (!first) {
                c0 = cfg[p * 128 + nb + col];
                c1 = cfg[p * 128 + nb + 16 + col];
            }
            cv2[mt][r] = (f32x2){c0, c1};
            zo2[mt][r] = (f32x2){c0, c1};
            Z32w[row * 68 + 16 * w + col] = pack_bf(c0, c1);
        }
    __syncthreads();

    f32x4 acc[2][2];
    auto matmul = [&](const unsigned short* Zr) {
        short8_t af[2][4];
        #pragma unroll
        for (int mt = 0; mt < 2; ++mt)
            #pragma unroll
            for (int s = 0; s < 4; ++s)
                af[mt][s] = *(const short8_t*)&Zr[(mt * 16 + col) * 136 + s * 32 + quad * 8];
        #pragma unroll
        for (int mt = 0; mt < 2; ++mt)
            #pragma unroll
            for (int nt = 0; nt < 2; ++nt)
                acc[mt][nt] = (f32x4){0.f, 0.f, 0.f, 0.f};
        #pragma unroll
        for (int s = 0; s < 4; ++s)
            #pragma unroll
            for (int mt = 0; mt < 2; ++mt)
                #pragma unroll
                for (int nt = 0; nt < 2; ++nt)
                    acc[mt][nt] = __builtin_amdgcn_mfma_f32_16x16x32_bf16(
                        af[mt][s], xf[nt][s], acc[mt][nt], 0, 0, 0);
    };

    float tm = 1.0f;
    int cur = 0;
    #pragma unroll 1
    for (int it = 0; it < 14; ++it) {          // FISTA iters 1..14 (write z)
        matmul(Zbuf[cur]);
        float tnn = 0.5f * (1.0f + sqrtf(1.0f + 4.0f * tm * tm));
        float fm = (tm - 1.0f) / tnn;
        tm = tnn;
        f32x2 fm2 = (f32x2){fm, fm};
        uint32_t* Zw = (uint32_t*)Zbuf[cur ^ 1];
        #pragma unroll
        for (int mt = 0; mt < 2; ++mt)
            #pragma unroll
            for (int r = 0; r < 4; ++r) {
                f32x2 a2 = (f32x2){acc[mt][0][r], acc[mt][1][r]};
                f32x2 u2 = mu2 * (qv2[mt][r] - a2) + zo2[mt][r];
                f32x2 cl2 = __builtin_elementwise_min(
                                __builtin_elementwise_max(u2, nlam2), lam2);
                f32x2 cn2 = u2 - cl2;
                f32x2 zn2 = fm2 * (cn2 - cv2[mt][r]) + cn2;
                cv2[mt][r] = cn2;
                zo2[mt][r] = zn2;
                Zw[(mt * 16 + quad * 4 + r) * 68 + 16 * w + col] = pack_bf(zn2[0], zn2[1]);
            }
        __syncthreads();
        cur ^= 1;
    }
    {   // FISTA iter 15: compute c15; stage c15 (z15 never consumed)
        matmul(Zbuf[cur]);
        uint32_t* Zw = (uint32_t*)Zbuf[cur ^ 1];
        #pragma unroll
        for (int mt = 0; mt < 2; ++mt)
            #pragma unroll
            for (int r = 0; r < 4; ++r) {
                f32x2 a2 = (f32x2){acc[mt][0][r], acc[mt][1][r]};
                f32x2 u2 = mu2 * (qv2[mt][r] - a2) + zo2[mt][r];
                f32x2 cl2 = __builtin_elementwise_min(
                                __builtin_elementwise_max(u2, nlam2), lam2);
                f32x2 cn2 = u2 - cl2;
                cv2[mt][r] = cn2;
                Zw[(mt * 16 + quad * 4 + r) * 68 + 16 * w + col] = pack_bf(cn2[0], cn2[1]);
            }
        __syncthreads();
        cur ^= 1;
    }
    {   // final differentiable step: cf = prox(c15 + mu*(q - X@c15)); stage cf
        matmul(Zbuf[cur]);
        uint32_t* Zw = (uint32_t*)Zbuf[cur ^ 1];
        #pragma unroll
        for (int mt = 0; mt < 2; ++mt)
            #pragma unroll
            for (int r = 0; r < 4; ++r) {
                int row = mt * 16 + quad * 4 + r;
                f32x2 a2 = (f32x2){acc[mt][0][r], acc[mt][1][r]};
                f32x2 u2 = mu2 * (qv2[mt][r] - a2) + cv2[mt][r];
                f32x2 cl2 = __builtin_elementwise_min(
                                __builtin_elementwise_max(u2, nlam2), lam2);
                f32x2 cf2 = u2 - cl2;
                if (write_cf) {
                    cfg[(p0 + row) * 128 + nb + col] = cf2[0];
                    cfg[(p0 + row) * 128 + nb + 16 + col] = cf2[1];
                }
                Zw[row * 68 + 16 * w + col] = pack_bf(cf2[0], cf2[1]);
            }
        __syncthreads();
        cur ^= 1;
    }

    // ---- pred tail: pred[32][144] = cf @ atoms_n + pm (B pre-permuted ANTBP) ----
    {
        int jt0 = (w == 0) ? 0 : (2 * w + 1);
        int jtn = (w == 0) ? 3 : 2;
        const unsigned short* Zr = Zbuf[cur];
        short8_t af[2][4];
        #pragma unroll
        for (int mt = 0; mt < 2; ++mt)
            #pragma unroll
            for (int s = 0; s < 4; ++s)
                af[mt][s] = *(const short8_t*)&Zr[(mt * 16 + col) * 136 + s * 32 + quad * 8];
        f32x4 accp[2][3];
        #pragma unroll
        for (int mt = 0; mt < 2; ++mt)
            #pragma unroll
            for (int ji = 0; ji < 3; ++ji)
                accp[mt][ji] = (f32x4){0.f, 0.f, 0.f, 0.f};
        #pragma unroll
        for (int ji = 0; ji < 3; ++ji) {
            if (ji < jtn) {
                int jt = jt0 + ji;
                short8_t bf4[4];
                #pragma unroll
                for (int s = 0; s < 4; ++s)
                    bf4[s] = *(const short8_t*)&ANTBP[(jt * 16 + col) * 128 + s * 32 + quad * 8];
                #pragma unroll
                for (int mt = 0; mt < 2; ++mt)
                    #pragma unroll
                    for (int s = 0; s < 4; ++s)
                        accp[mt][ji] = __builtin_amdgcn_mfma_f32_16x16x32_bf16(
                            af[mt][s], bf4[s], accp[mt][ji], 0, 0, 0);
            }
        }
        #pragma unroll
        for (int mt = 0; mt < 2; ++mt)
            #pragma unroll
            for (int r = 0; r < 4; ++r) {
                int p = p0 + mt * 16 + quad * 4 + r;
                float pmv = pm[p];
                #pragma unroll
                for (int ji = 0; ji < 3; ++ji)
                    if (ji < jtn)
                        pred[p * 144 + (jt0 + ji) * 16 + col] = accp[mt][ji][r] + pmv;
            }
    }
}

// ---- fold via LDS staging: block = (output row i, batch b); coalesced pred reads. ----
__global__ __launch_bounds__(256) void k_fold(const float* y, const float* beta_p,
                                              const float* pred, float* goal,
                                              float* out, int write_out) {
    __shared__ float P[12 * 832];              // 39,936 B
    int i = blockIdx.x, b = blockIdx.y;
    int t = threadIdx.x;
    for (int di = 0; di < 12; ++di) {
        int pi = i - di;
        if ((unsigned)pi >= 64u) continue;     // uniform per block
        int base = (b << 12) + (pi << 6);
        #pragma unroll
        for (int it = 0; it < 3; ++it) {
            int e = t + it * 256;              // < 768 = 64 pj * 12 dj
            int pj = e / 12, dj = e - pj * 12;
            P[di * 832 + pj * 13 + dj] = pred[(base + pj) * AA + di * 12 + dj];
        }
    }
    __syncthreads();
    if (t >= 75) return;
    int j = t;
    float S = 0.f;
    for (int di = 0; di < 12; ++di) {
        if ((unsigned)(i - di) >= 64u) continue;
        const float* Pd = &P[di * 832];
        #pragma unroll
        for (int dj = 0; dj < 12; ++dj) {
            int pj = j - dj;
            if ((unsigned)pj >= 64u) continue;
            S += Pd[pj * 13 + dj];
        }
    }
    int ci = min(i, 11) - max(i - 63, 0) + 1;
    int cj = min(j, 11) - max(j - 63, 0) + 1;
    float beta = fmaxf(beta_p[0], 0.0f);
    int idx = i * 75 + j;
    float yv = y[b * 5625 + idx];
    float g = (yv + beta * S) / (1.0f + beta * (float)(ci * cj));
    if (write_out) out[b * 5625 + idx] = g;
    else           goal[b * 5625 + idx] = g;
}

extern "C" void kernel_launch(void* const* d_in, const int* in_sizes, int n_in,
                              void* d_out, int out_size, void* d_ws, size_t ws_size,
                              hipStream_t stream) {
    const float* y     = (const float*)d_in[0];
    const float* atoms = (const float*)d_in[1];
    const float* beta  = (const float*)d_in[2];
    const float* mu    = (const float*)d_in[3];
    float* out = (float*)d_out;
    float* ws = (float*)d_ws;

    k_setup<<<46, 1024, 0, stream>>>(atoms, mu, ws, y);   // block0 chain + workers goal/pm
    k_finalize<<<216, 256, 0, stream>>>(ws);              // XPB + ATB + ANTBP

    for (int u = 0; u < 2; ++u) {
        k_fista<<<1024, 256, 0, stream>>>((const unsigned short*)(ws + OFS_X),
                                          ws + OFS_GOAL,
                                          (const unsigned short*)(ws + OFS_ATB),
                                          (const unsigned short*)(ws + OFS_ANTB),
                                          ws + OFS_PM, ws + OFS_CF, ws + OFS_PRED,
                                          mu, u == 0 ? 1 : 0, u == 0 ? 1 : 0);
        k_fold<<<dim3(75, 8), 256, 0, stream>>>(y, beta, ws + OFS_PRED,
                                                ws + OFS_GOAL, out, u == 1 ? 1 : 0);
    }
}

// Round 18
// 211.835 us; speedup vs baseline: 1.3546x; 1.0106x over previous
//
#include <hip/hip_runtime.h>
#include <stdint.h>

// Problem constants
#define AA 144          // ATOM*ATOM
#define LAM 0.1f

// ---- workspace layout (float offsets) ----
#define OFS_SC    0            // 64 scalars: [16]=scX, [17]=scA
#define OFS_AF1   64           // 128*144 row-normalized zero-mean atoms
#define OFS_G     36928        // 128*128 gram (f32)
#define OFS_S0    53312        // ATB (bf16 atoms, [128][160] u16)
#define OFS_S1    69696        // ANTBP (bf16 atomsT, n-permuted, [144][128] u16)
#define OFS_X     86080        // XPB: bf16 X, k-permuted, [128][128] u16
#define OFS_PM    139328       // 32768 patch means
#define OFS_GOAL  172096       // 45056 goal (f32)
#define OFS_CF    4411456      // cfgb: packed bf16 pairs [32768][64] u32
#define OFS_PRED  8605760      // predh: bf16 [32768][144] u16
#define OFS_ATB   OFS_S0
#define OFS_ANTB  OFS_S1

// Contraction-dim permutation: real n = 32g + 16v + u  <->  stored ks = 32g + 2u + v.
// A and B sides both use stored order -> dot products unchanged.

typedef __attribute__((ext_vector_type(8))) short short8_t;
typedef __attribute__((ext_vector_type(4))) float f32x4;
typedef __attribute__((ext_vector_type(2))) float f32x2;

__device__ __forceinline__ unsigned short f2bf(float f) {      // RNE
    union { float f; uint32_t u; } x; x.f = f;
    uint32_t u = x.u;
    return (unsigned short)((u + 0x7FFFu + ((u >> 16) & 1u)) >> 16);
}
__device__ __forceinline__ unsigned short f2bh(float f) {      // round-half-up (cheap)
    union { float f; uint32_t u; } x; x.f = f;
    return (unsigned short)((x.u + 0x8000u) >> 16);
}
__device__ __forceinline__ float bf2f(unsigned short u) {
    union { float f; uint32_t i; } x; x.i = ((uint32_t)u) << 16; return x.f;
}
// pack two f32 -> packed bf16 pair (a->low, b->high), round-half-up
__device__ __forceinline__ uint32_t pack_bf(float a, float b) {
    union { float f; uint32_t u; } xa, xb; xa.f = a; xb.f = b;
    return __builtin_amdgcn_perm(xb.u + 0x8000u, xa.u + 0x8000u, 0x07060302u);
}

// ---- setup: block 0 = norm + bf16 gram + 8x power squarings + Rayleigh (1024 thr);
//      blocks 1..45 = goal copy + patch means (run hidden under block 0's chain). ----
#define PSTR 136
__global__ __launch_bounds__(1024) void k_setup(const float* atoms, const float* mu_p,
                                                float* ws, const float* y) {
    __shared__ unsigned short ABf[128 * 168];       // 43008 B
    __shared__ unsigned short Pb[2][128 * PSTR];    // 69632 B
    __shared__ float tr_arr[10];
    __shared__ float v[128];
    __shared__ float red[256];
    int t = threadIdx.x;
    if (blockIdx.x != 0) {                          // worker blocks: goal + pm
        int e = (blockIdx.x - 1) * 1024 + t;        // < 46080
        if (e < 45000) ws[OFS_GOAL + e] = y[e];
        if (e < 32768) {
            int b = e >> 12, pi = (e >> 6) & 63, pj = e & 63;
            const float* yb = y + b * 5625;
            float s = 0.f;
            for (int di = 0; di < 12; ++di) {
                const float* row = yb + (pi + di) * 75 + pj;
                #pragma unroll
                for (int dj = 0; dj < 12; ++dj) s += row[dj];
            }
            ws[OFS_PM + e] = s * (1.0f / 144.0f);
        }
        return;
    }
    int lane = t & 63, w = t >> 6;
    int col = lane & 15, quad = lane >> 4;
    if (t < 10) tr_arr[t] = (t == 0) ? 128.0f : 0.f;

    // ---- norm: 8 threads/atom, width-8 shfl reductions ----
    {
        int a = t >> 3, sub = t & 7;
        const float* ap = atoms + a * AA + sub * 18;
        float s = 0.f;
        #pragma unroll
        for (int k = 0; k < 18; ++k) s += ap[k];
        s += __shfl_xor(s, 1, 8); s += __shfl_xor(s, 2, 8); s += __shfl_xor(s, 4, 8);
        float mean = s * (1.0f / 144.0f);
        float ss = 0.f;
        #pragma unroll
        for (int k = 0; k < 18; ++k) { float d = ap[k] - mean; ss = fmaf(d, d, ss); }
        ss += __shfl_xor(ss, 1, 8); ss += __shfl_xor(ss, 2, 8); ss += __shfl_xor(ss, 4, 8);
        float rn = 1.0f / sqrtf(ss);
        #pragma unroll
        for (int k = 0; k < 18; ++k) {
            float av = (ap[k] - mean) * rn;
            ws[OFS_AF1 + a * AA + sub * 18 + k] = av;
            ABf[a * 168 + sub * 18 + k] = f2bf(av);
        }
        if (sub == 0) {
            #pragma unroll
            for (int k = AA; k < 160; ++k) ABf[a * 168 + k] = 0;
        }
    }
    __syncthreads();

    // ---- gram: wave w -> m-tile (w&7), g-half (w>>3) ----
    {
        uint32_t* D32 = (uint32_t*)Pb[0];
        float* G = ws + OFS_G;
        int mt = w & 7, gh = w >> 3;
        short8_t af[5];
        #pragma unroll
        for (int s = 0; s < 5; ++s)
            af[s] = *(const short8_t*)&ABf[(mt * 16 + col) * 168 + s * 32 + quad * 8];
        #pragma unroll
        for (int gi = 0; gi < 2; ++gi) {
            int g = gh * 2 + gi;
            short8_t b0[5], b1[5];
            #pragma unroll
            for (int s = 0; s < 5; ++s) {
                b0[s] = *(const short8_t*)&ABf[((2 * g) * 16 + col) * 168 + s * 32 + quad * 8];
                b1[s] = *(const short8_t*)&ABf[((2 * g + 1) * 16 + col) * 168 + s * 32 + quad * 8];
            }
            f32x4 a0 = (f32x4){0.f, 0.f, 0.f, 0.f};
            f32x4 a1 = (f32x4){0.f, 0.f, 0.f, 0.f};
            #pragma unroll
            for (int s = 0; s < 5; ++s) {
                a0 = __builtin_amdgcn_mfma_f32_16x16x32_bf16(af[s], b0[s], a0, 0, 0, 0);
                a1 = __builtin_amdgcn_mfma_f32_16x16x32_bf16(af[s], b1[s], a1, 0, 0, 0);
            }
            #pragma unroll
            for (int r = 0; r < 4; ++r) {
                int m = mt * 16 + quad * 4 + r;
                G[m * 128 + g * 32 + col] = a0[r];
                G[m * 128 + g * 32 + 16 + col] = a1[r];
                D32[m * 68 + g * 16 + col] = pack_bf(a0[r], a1[r]);
            }
        }
    }
    __syncthreads();

    // ---- power: 8 squarings; wave w -> m-tile (w&7), n-quarter (w>>3) ----
    int cur = 0;
    #pragma unroll 1
    for (int j = 0; j < 8; ++j) {
        float trn = tr_arr[j];
        float inv2 = 1.0f / (trn * trn);
        const unsigned short* S = Pb[cur];
        uint32_t* D32 = (uint32_t*)Pb[cur ^ 1];
        int mt = w & 7, nh = w >> 3;
        short8_t af[4];
        #pragma unroll
        for (int s = 0; s < 4; ++s)
            af[s] = *(const short8_t*)&S[(mt * 16 + col) * PSTR + s * 32 + quad * 8];
        #pragma unroll
        for (int pr = 0; pr < 2; ++pr) {
            int ntE = 4 * nh + 2 * pr, ntO = ntE + 1;
            short8_t bE[4], bO[4];
            #pragma unroll
            for (int s = 0; s < 4; ++s) {
                bE[s] = *(const short8_t*)&S[(ntE * 16 + col) * PSTR + s * 32 + quad * 8];
                bO[s] = *(const short8_t*)&S[(ntO * 16 + col) * PSTR + s * 32 + quad * 8];
            }
            f32x4 aE = (f32x4){0.f, 0.f, 0.f, 0.f};
            f32x4 aO = (f32x4){0.f, 0.f, 0.f, 0.f};
            #pragma unroll
            for (int s = 0; s < 4; ++s) {
                aE = __builtin_amdgcn_mfma_f32_16x16x32_bf16(af[s], bE[s], aE, 0, 0, 0);
                aO = __builtin_amdgcn_mfma_f32_16x16x32_bf16(af[s], bO[s], aO, 0, 0, 0);
            }
            int nE = ntE * 16 + col, nO = ntO * 16 + col;
            #pragma unroll
            for (int r = 0; r < 4; ++r) {
                float x0 = aE[r] * inv2, x1 = aO[r] * inv2;
                int row = mt * 16 + quad * 4 + r;
                D32[row * 68 + (ntE >> 1) * 16 + col] = pack_bf(x0, x1);
                if (row == nE) atomicAdd(&tr_arr[j + 1], x0);
                if (row == nO) atomicAdd(&tr_arr[j + 1], x1);
            }
        }
        __syncthreads();
        cur ^= 1;
    }

    // ---- Rayleigh on f32 G (8 threads/row) ----
    {
        int a = t >> 3, sub = t & 7;
        const unsigned short* S = Pb[cur];
        float s = 0.f;
        #pragma unroll
        for (int k = 0; k < 16; ++k) s += bf2f(S[a * PSTR + sub * 16 + k]);
        s += __shfl_xor(s, 1, 8); s += __shfl_xor(s, 2, 8); s += __shfl_xor(s, 4, 8);
        if (sub == 0) v[a] = s;
    }
    __syncthreads();
    {
        int a = t >> 3, sub = t & 7;
        const float* G = ws + OFS_G;
        float wv = 0.f;
        #pragma unroll
        for (int k = 0; k < 16; ++k)
            wv = fmaf(G[a * 128 + sub * 16 + k], v[sub * 16 + k], wv);
        wv += __shfl_xor(wv, 1, 8); wv += __shfl_xor(wv, 2, 8); wv += __shfl_xor(wv, 4, 8);
        if (sub == 0) { red[a] = v[a] * wv; red[128 + a] = v[a] * v[a]; }
    }
    __syncthreads();
    for (int off = 64; off > 0; off >>= 1) {
        if (t < off) { red[t] += red[t + off]; red[128 + t] += red[128 + t + off]; }
        __syncthreads();
    }
    if (t == 0) {
        float lam = red[0] / red[128];
        float mu = fmaxf(mu_p[0], 0.0f);
        ws[OFS_SC + 16] = 1.0f / (lam * mu);
        ws[OFS_SC + 17] = 1.0f / (sqrtf(lam) * sqrtf(mu));
    }
}

// ---- finalize: only the scale-dependent tables (XPB / ATB / ANTBP) ----
__global__ __launch_bounds__(256) void k_finalize(float* ws) {
    int idx = blockIdx.x * 256 + threadIdx.x;       // grid 216 -> 55296
    float scX = ws[OFS_SC + 16], scA = ws[OFS_SC + 17];
    if (idx < 16384) {
        int n = idx >> 7, ks = idx & 127;
        int g = ks >> 5, rem = ks & 31, u = rem >> 1, v = rem & 1;
        int k = g * 32 + v * 16 + u;
        ((unsigned short*)(ws + OFS_X))[idx] = f2bf(ws[OFS_G + n * 128 + k] * scX);
    } else if (idx < 36864) {
        int e = idx - 16384;                        // ATB [n=128][k=160] zero-pad
        int n = e / 160, k = e - n * 160;
        float v = (k < 144) ? ws[OFS_AF1 + n * 144 + k] * scA : 0.f;
        ((unsigned short*)(ws + OFS_ATB))[e] = f2bf(v);
    } else {
        int e = idx - 36864;                        // ANTBP [j=144][ks=128]
        int jp = e >> 7, ks = e & 127;
        int g = ks >> 5, rem = ks & 31, u = rem >> 1, v = rem & 1;
        int n = g * 32 + v * 16 + u;
        ((unsigned short*)(ws + OFS_ANTB))[e] = f2bf(ws[OFS_AF1 + n * 144 + jp] * scA);
    }
}

// ---- fused megakernel: q (im2col MFMA, direct-from-goal) + FISTA(15)+1 + pred(bf16).
//      cfg as packed bf16 pairs (u32) between unrolls. ----
__global__ __launch_bounds__(256) void k_fista(const unsigned short* XPB, const float* goal,
                                               const unsigned short* ATB,
                                               const unsigned short* ANTBP,
                                               const float* pm, uint32_t* cfgb,
                                               unsigned short* predh,
                                               const float* mu_p, int first, int write_cf) {
    __shared__ unsigned short Atile[32 * 168];
    __shared__ unsigned short Zbuf[2][32 * 136];
    int t = threadIdx.x;
    int lane = t & 63, w = t >> 6;
    int col = lane & 15, quad = lane >> 4;
    int nb = w * 32;
    int blk = blockIdx.x;
    int b = blk >> 7, pi = (blk >> 1) & 63, h = blk & 1;
    int p0 = blk * 32;
    float mu = fmaxf(mu_p[0], 0.0f);
    const f32x2 mu2 = (f32x2){mu, mu};
    const f32x2 lam2 = (f32x2){LAM, LAM};
    const f32x2 nlam2 = (f32x2){-LAM, -LAM};

    // ---- im2col A-tile 32 x 160 bf16 directly from goal (no staging; max col
    //      = 32+31+11 = 74 < 75, so no bounds check needed) ----
    {
        const float* gb = goal + b * 5625 + pi * 75 + h * 32;
        uint32_t* A32 = (uint32_t*)Atile;          // row stride 84 u32
        #pragma unroll
        for (int i = 0; i < 10; ++i) {
            int pe = t + i * 256;                  // < 2560 = 32m * 80 pairs
            int m = pe / 80, q32 = pe - m * 80;
            int kk = q32 * 2;
            float v0 = 0.f, v1 = 0.f;
            if (kk < 144) {
                int di = kk / 12, dj = kk - di * 12;
                v0 = gb[di * 75 + m + dj];
                int k1 = kk + 1, di1 = k1 / 12, dj1 = k1 - di1 * 12;
                v1 = gb[di1 * 75 + m + dj1];
            }
            A32[m * 84 + q32] = pack_bf(v0, v1);
        }
    }
    __syncthreads();

    // ---- q-matmul: qv2[mt][r] = {q(nt0), q(nt1)} in C/D layout ----
    f32x2 qv2[2][4];
    {
        short8_t bfq[2][5];
        #pragma unroll
        for (int nt = 0; nt < 2; ++nt)
            #pragma unroll
            for (int s = 0; s < 5; ++s)
                bfq[nt][s] = *(const short8_t*)&ATB[(nb + nt * 16 + col) * 160 + s * 32 + quad * 8];
        #pragma unroll
        for (int mt = 0; mt < 2; ++mt) {
            short8_t af[5];
            #pragma unroll
            for (int s = 0; s < 5; ++s)
                af[s] = *(const short8_t*)&Atile[(mt * 16 + col) * 168 + s * 32 + quad * 8];
            f32x4 acc0 = (f32x4){0.f, 0.f, 0.f, 0.f};
            f32x4 acc1 = (f32x4){0.f, 0.f, 0.f, 0.f};
            #pragma unroll
            for (int s = 0; s < 5; ++s) {
                acc0 = __builtin_amdgcn_mfma_f32_16x16x32_bf16(af[s], bfq[0][s], acc0, 0, 0, 0);
                acc1 = __builtin_amdgcn_mfma_f32_16x16x32_bf16(af[s], bfq[1][s], acc1, 0, 0, 0);
            }
            #pragma unroll
            for (int r = 0; r < 4; ++r) qv2[mt][r] = (f32x2){acc0[r], acc1[r]};
        }
    }

    // ---- X B-fragments: contiguous b128 from pre-permuted bf16 XPB ----
    short8_t xf[2][4];
    #pragma unroll
    for (int nt = 0; nt < 2; ++nt)
        #pragma unroll
        for (int s = 0; s < 4; ++s)
            xf[nt][s] = *(const short8_t*)&XPB[(nb + nt * 16 + col) * 128 + s * 32 + quad * 8];

    // ---- c0 / z0 init, seed Z (packed bf16 pairs from cfgb) ----
    uint32_t* Z32w = (uint32_t*)Zbuf[0];           // row stride 68 u32
    f32x2 cv2[2][4], zo2[2][4];
    #pragma unroll
    for (int mt = 0; mt < 2; ++mt)
        #pragma unroll
        for (int r = 0; r < 4; ++r) {
            int row = mt * 16 + quad * 4 + r;
            uint32_t pk = 0u;
            float c0 = 0.f, c1 = 0.f;
            if (!first) {
                pk = cfgb[(p0 + row) * 64 + 16 * w + col];
                c0 = bf2f((unsigned short)(pk & 0xFFFFu));
                c1 = bf2f((unsigned short)(pk >> 16));
            }
            cv2[mt][r] = (f32x2){c0, c1};
            zo2[mt][r] = (f32x2){c0, c1};
            Z32w[row * 68 + 16 * w + col] = pk;
        }
    __syncthreads();

    f32x4 acc[2][2];
    auto matmul = [&](const unsigned short* Zr) {
        short8_t af[2][4];
        #pragma unroll
        for (int mt = 0; mt < 2; ++mt)
            #pragma unroll
            for (int s = 0; s < 4; ++s)
                af[mt][s] = *(const short8_t*)&Zr[(mt * 16 + col) * 136 + s * 32 + quad * 8];
        #pragma unroll
        for (int mt = 0; mt < 2; ++mt)
            #pragma unroll
            for (int nt = 0; nt < 2; ++nt)
                acc[mt][nt] = (f32x4){0.f, 0.f, 0.f, 0.f};
        #pragma unroll
        for (int s = 0; s < 4; ++s)
            #pragma unroll
            for (int mt = 0; mt < 2; ++mt)
                #pragma unroll
                for (int nt = 0; nt < 2; ++nt)
                    acc[mt][nt] = __builtin_amdgcn_mfma_f32_16x16x32_bf16(
                        af[mt][s], xf[nt][s], acc[mt][nt], 0, 0, 0);
    };

    float tm = 1.0f;
    int cur = 0;
    #pragma unroll 1
    for (int it = 0; it < 14; ++it) {          // FISTA iters 1..14 (write z)
        matmul(Zbuf[cur]);
        float tnn = 0.5f * (1.0f + sqrtf(1.0f + 4.0f * tm * tm));
        float fm = (tm - 1.0f) / tnn;
        tm = tnn;
        f32x2 fm2 = (f32x2){fm, fm};
        uint32_t* Zw = (uint32_t*)Zbuf[cur ^ 1];
        #pragma unroll
        for (int mt = 0; mt < 2; ++mt)
            #pragma unroll
            for (int r = 0; r < 4; ++r) {
                f32x2 a2 = (f32x2){acc[mt][0][r], acc[mt][1][r]};
                f32x2 u2 = mu2 * (qv2[mt][r] - a2) + zo2[mt][r];
                f32x2 cl2 = __builtin_elementwise_min(
                                __builtin_elementwise_max(u2, nlam2), lam2);
                f32x2 cn2 = u2 - cl2;
                f32x2 zn2 = fm2 * (cn2 - cv2[mt][r]) + cn2;
                cv2[mt][r] = cn2;
                zo2[mt][r] = zn2;
                Zw[(mt * 16 + quad * 4 + r) * 68 + 16 * w + col] = pack_bf(zn2[0], zn2[1]);
            }
        __syncthreads();
        cur ^= 1;
    }
    {   // FISTA iter 15: compute c15; stage c15 (z15 never consumed)
        matmul(Zbuf[cur]);
        uint32_t* Zw = (uint32_t*)Zbuf[cur ^ 1];
        #pragma unroll
        for (int mt = 0; mt < 2; ++mt)
            #pragma unroll
            for (int r = 0; r < 4; ++r) {
                f32x2 a2 = (f32x2){acc[mt][0][r], acc[mt][1][r]};
                f32x2 u2 = mu2 * (qv2[mt][r] - a2) + zo2[mt][r];
                f32x2 cl2 = __builtin_elementwise_min(
                                __builtin_elementwise_max(u2, nlam2), lam2);
                f32x2 cn2 = u2 - cl2;
                cv2[mt][r] = cn2;
                Zw[(mt * 16 + quad * 4 + r) * 68 + 16 * w + col] = pack_bf(cn2[0], cn2[1]);
            }
        __syncthreads();
        cur ^= 1;
    }
    {   // final differentiable step: cf = prox(c15 + mu*(q - X@c15)); stage cf
        matmul(Zbuf[cur]);
        uint32_t* Zw = (uint32_t*)Zbuf[cur ^ 1];
        #pragma unroll
        for (int mt = 0; mt < 2; ++mt)
            #pragma unroll
            for (int r = 0; r < 4; ++r) {
                int row = mt * 16 + quad * 4 + r;
                f32x2 a2 = (f32x2){acc[mt][0][r], acc[mt][1][r]};
                f32x2 u2 = mu2 * (qv2[mt][r] - a2) + cv2[mt][r];
                f32x2 cl2 = __builtin_elementwise_min(
                                __builtin_elementwise_max(u2, nlam2), lam2);
                f32x2 cf2 = u2 - cl2;
                uint32_t pk = pack_bf(cf2[0], cf2[1]);
                if (write_cf) cfgb[(p0 + row) * 64 + 16 * w + col] = pk;
                Zw[row * 68 + 16 * w + col] = pk;
            }
        __syncthreads();
        cur ^= 1;
    }

    // ---- pred tail: predh[32][144] = bf16(cf @ atoms_n + pm) ----
    {
        int jt0 = (w == 0) ? 0 : (2 * w + 1);
        int jtn = (w == 0) ? 3 : 2;
        const unsigned short* Zr = Zbuf[cur];
        short8_t af[2][4];
        #pragma unroll
        for (int mt = 0; mt < 2; ++mt)
            #pragma unroll
            for (int s = 0; s < 4; ++s)
                af[mt][s] = *(const short8_t*)&Zr[(mt * 16 + col) * 136 + s * 32 + quad * 8];
        f32x4 accp[2][3];
        #pragma unroll
        for (int mt = 0; mt < 2; ++mt)
            #pragma unroll
            for (int ji = 0; ji < 3; ++ji)
                accp[mt][ji] = (f32x4){0.f, 0.f, 0.f, 0.f};
        #pragma unroll
        for (int ji = 0; ji < 3; ++ji) {
            if (ji < jtn) {
                int jt = jt0 + ji;
                short8_t bf4[4];
                #pragma unroll
                for (int s = 0; s < 4; ++s)
                    bf4[s] = *(const short8_t*)&ANTBP[(jt * 16 + col) * 128 + s * 32 + quad * 8];
                #pragma unroll
                for (int mt = 0; mt < 2; ++mt)
                    #pragma unroll
                    for (int s = 0; s < 4; ++s)
                        accp[mt][ji] = __builtin_amdgcn_mfma_f32_16x16x32_bf16(
                            af[mt][s], bf4[s], accp[mt][ji], 0, 0, 0);
            }
        }
        #pragma unroll
        for (int mt = 0; mt < 2; ++mt)
            #pragma unroll
            for (int r = 0; r < 4; ++r) {
                int p = p0 + mt * 16 + quad * 4 + r;
                float pmv = pm[p];
                #pragma unroll
                for (int ji = 0; ji < 3; ++ji)
                    if (ji < jtn)
                        predh[p * 144 + (jt0 + ji) * 16 + col] = f2bh(accp[mt][ji][r] + pmv);
            }
    }
}

// ---- fold via LDS staging: block = (output row i, batch b); bf16 pred reads. ----
__global__ __launch_bounds__(256) void k_fold(const float* y, const float* beta_p,
                                              const unsigned short* predh, float* goal,
                                              float* out, int write_out) {
    __shared__ float P[12 * 832];              // 39,936 B
    int i = blockIdx.x, b = blockIdx.y;
    int t = threadIdx.x;
    for (int di = 0; di < 12; ++di) {
        int pi = i - di;
        if ((unsigned)pi >= 64u) continue;     // uniform per block
        int base = (b << 12) + (pi << 6);
        #pragma unroll
        for (int it = 0; it < 3; ++it) {
            int e = t + it * 256;              // < 768 = 64 pj * 12 dj
            int pj = e / 12, dj = e - pj * 12;
            P[di * 832 + pj * 13 + dj] = bf2f(predh[(base + pj) * AA + di * 12 + dj]);
        }
    }
    __syncthreads();
    if (t >= 75) return;
    int j = t;
    float S = 0.f;
    for (int di = 0; di < 12; ++di) {
        if ((unsigned)(i - di) >= 64u) continue;
        const float* Pd = &P[di * 832];
        #pragma unroll
        for (int dj = 0; dj < 12; ++dj) {
            int pj = j - dj;
            if ((unsigned)pj >= 64u) continue;
            S += Pd[pj * 13 + dj];
        }
    }
    int ci = min(i, 11) - max(i - 63, 0) + 1;
    int cj = min(j, 11) - max(j - 63, 0) + 1;
    float beta = fmaxf(beta_p[0], 0.0f);
    int idx = i * 75 + j;
    float yv = y[b * 5625 + idx];
    float g = (yv + beta * S) / (1.0f + beta * (float)(ci * cj));
    if (write_out) out[b * 5625 + idx] = g;
    else           goal[b * 5625 + idx] = g;
}

extern "C" void kernel_launch(void* const* d_in, const int* in_sizes, int n_in,
                              void* d_out, int out_size, void* d_ws, size_t ws_size,
                              hipStream_t stream) {
    const float* y     = (const float*)d_in[0];
    const float* atoms = (const float*)d_in[1];
    const float* beta  = (const float*)d_in[2];
    const float* mu    = (const float*)d_in[3];
    float* out = (float*)d_out;
    float* ws = (float*)d_ws;

    k_setup<<<46, 1024, 0, stream>>>(atoms, mu, ws, y);   // block0 chain + workers goal/pm
    k_finalize<<<216, 256, 0, stream>>>(ws);              // XPB + ATB + ANTBP

    for (int u = 0; u < 2; ++u) {
        k_fista<<<1024, 256, 0, stream>>>((const unsigned short*)(ws + OFS_X),
                                          ws + OFS_GOAL,
                                          (const unsigned short*)(ws + OFS_ATB),
                                          (const unsigned short*)(ws + OFS_ANTB),
                                          ws + OFS_PM, (uint32_t*)(ws + OFS_CF),
                                          (unsigned short*)(ws + OFS_PRED),
                                          mu, u == 0 ? 1 : 0, u == 0 ? 1 : 0);
        k_fold<<<dim3(75, 8), 256, 0, stream>>>(y, beta,
                                                (const unsigned short*)(ws + OFS_PRED),
                                                ws + OFS_GOAL, out, u == 1 ? 1 : 0);
    }
}